// Round 13
// baseline (364.948 us; speedup 1.0000x reference)
//
#include <hip/hip_runtime.h>
#include <hip/hip_bf16.h>

// ImprovedCobrablock on MI355X (gfx950).
// Inputs/output f32 (verified r3). bf16 MFMA GEMMs, f32 scan state.
// GEMM: register staging + prefetch (r5), BK=64 (r11), XOR swizzle (r12,
// neutral but kept — conflict counter proved write-side-inherent).
// Conv folded into Wcomb (r7). Fat-thread scan NCH=64 (r8). MT=64 + z/conv
// merge (r9). gemm_gu fusion (r10).
// r13: single-barrier DOUBLE-BUFFERED LDS in gemm_bt/gemm_xz — r12 showed
// 60% of gemm_xz cycles are stall with 2 barriers/stage + vmcnt drain
// between them. Dbuf: read buf[s], write buf[s^1], ONE barrier/stage.
// gemm_gu stays single-buffer (dbuf would exceed 64KB static LDS).
// B=4, L=2048, D=384, Di=768, N=16, K=4, FFN=1024, T=8192.

using u16 = unsigned short;
using u32 = unsigned int;
using short8 = __attribute__((ext_vector_type(8))) short;
using f32x4  = __attribute__((ext_vector_type(4))) float;

#define TTOK 8192
#define DM 384
#define DI 768
#define NST 16
#define LSEQ 2048
#define NCH 64   /* chunks per sequence */
#define LCH 32   /* chunk length */

// LDS tile layout: [rows][32 u16], 4 chunks of 8 u16 per row, XOR-swizzled.
#define SWZ_R(row, quad) \
  ((row) * 32 + ((((quad) ^ (row) ^ ((row) >> 2)) & 3) * 8))
#define SWZ_W(tid) SWZ_R((tid) >> 2, (tid) & 3)

__device__ __forceinline__ float bf2f(u16 a) {
  u32 u = ((u32)a) << 16;
  float f; __builtin_memcpy(&f, &u, 4); return f;
}
__device__ __forceinline__ u16 f2bf(float f) {
  u32 u; __builtin_memcpy(&u, &f, 4);
  u32 r = (u + 0x7fffu + ((u >> 16) & 1u)) >> 16;  // RNE
  return (u16)r;
}
__device__ __forceinline__ int probe_bf(const void* rw) {
  return (((const u32*)rw)[0] == 0x3F803F80u) ? 1 : 0;
}
__device__ __forceinline__ float ld_in(const void* p, int i, int isbf) {
  return isbf ? bf2f(((const u16*)p)[i]) : ((const float*)p)[i];
}
__device__ __forceinline__ float fexp2(float x) {
#if __has_builtin(__builtin_amdgcn_exp2f)
  return __builtin_amdgcn_exp2f(x);
#else
  return exp2f(x);
#endif
}
__device__ __forceinline__ float wave_sum(float v) {
#pragma unroll
  for (int off = 32; off > 0; off >>= 1) v += __shfl_xor(v, off, 64);
  return v;
}

// ---------------------------------------------------------------- prep ----
__global__ __launch_bounds__(256) void k_prep(
    const void* __restrict__ in_proj, const void* __restrict__ conv_w,
    const void* __restrict__ dt_w, const void* __restrict__ x_proj,
    const void* __restrict__ out_proj, const void* __restrict__ gate_w,
    const void* __restrict__ up_w, const void* __restrict__ down_w,
    const void* __restrict__ A_log, const void* __restrict__ conv_b,
    const void* __restrict__ dt_b, const void* __restrict__ Dp,
    const void* __restrict__ rms1_w, const void* __restrict__ rms2_w,
    const void* __restrict__ gamma, const void* __restrict__ beta,
    u16* __restrict__ W1T, u16* __restrict__ WCT, u16* __restrict__ W45T,
    u16* __restrict__ W5T, u16* __restrict__ W6T, u16* __restrict__ W7T,
    float* __restrict__ An2T, u16* __restrict__ vecs,
    u16* __restrict__ WinX, u16* __restrict__ h1pad) {
  const int isbf = probe_bf(rms1_w);
  int idx = blockIdx.x * 256 + threadIdx.x;
#define XPOSE(base, n, src, dst, R, C)                         \
  if (idx < (base) + (n)) {                                    \
    int lo = idx - (base);                                     \
    int r = lo / (C), c = lo % (C);                            \
    dst[(size_t)c * (R) + r] = f2bf(ld_in(src, lo, isbf));     \
    return;                                                    \
  }
  XPOSE(0,       589824,  in_proj,  W1T, 384, 1536)
  if (idx < 2949120) {  // conv_w [4][768j][768n] -> WCT [4][768n][768j]
    int lo = idx - 589824;
    int t = lo / 589824, rem = lo % 589824;
    int j = rem / 768, n = rem % 768;
    WCT[(size_t)t * 589824 + n * 768 + j] = f2bf(ld_in(conv_w, lo, isbf));
    return;
  }
  XPOSE(2949120, 589824,  dt_w,     W45T, 768, 768)
  XPOSE(3538944, 24576,   x_proj,  (W45T + (size_t)768 * 768), 768, 32)
  XPOSE(3563520, 294912,  out_proj, W5T, 768, 384)
  XPOSE(3858432, 393216,  gate_w,   W6T, 384, 1024)
  XPOSE(4251648, 393216,  up_w,    (W6T + (size_t)1024 * 384), 384, 1024)
  XPOSE(4644864, 393216,  down_w,   W7T, 1024, 384)
#undef XPOSE
  if (idx < 5332992) {  // Win_x = in_proj[:, 0:768] as [384][768] bf16
    int lo = idx - 5038080;
    int i = lo / 768, j = lo % 768;
    WinX[lo] = f2bf(ld_in(in_proj, i * 1536 + j, isbf));
    return;
  }
  if (idx < 5345280) {  // A_log [768][16] -> An2T [16][768] = -exp * log2e
    int lo = idx - 5332992;
    int d = lo >> 4, n = lo & 15;
    An2T[n * DI + d] = -__expf(ld_in(A_log, lo, isbf)) * 1.44269504f;
    return;
  }
  if (idx < 5349120) {  // small vectors -> bf16, packed into vecs[]
    int lo = idx - 5345280;
    const void* s; int o;
    if      (lo < 768)  { s = conv_b; o = lo; }
    else if (lo < 1536) { s = dt_b;   o = lo - 768; }
    else if (lo < 2304) { s = Dp;     o = lo - 1536; }
    else if (lo < 2688) { s = rms1_w; o = lo - 2304; }
    else if (lo < 3072) { s = rms2_w; o = lo - 2688; }
    else if (lo < 3456) { s = gamma;  o = lo - 3072; }
    else                { s = beta;   o = lo - 3456; }
    vecs[lo] = f2bf(ld_in(s, o, isbf));
    return;
  }
  if (idx < 5353728) {  // h1pad halo rows 0, 2049, 2050 per batch -> 0
    int lo = idx - 5349120;
    int b = lo / (3 * DM), rem = lo % (3 * DM);
    int which = rem / DM, i = rem % DM;
    int row = b * 2051 + (which == 0 ? 0 : (2048 + which));
    h1pad[(size_t)row * DM + i] = 0;
  }
}

// vecs[] layout offsets
#define V_CB 0
#define V_DB 768
#define V_DP 1536
#define V_R1 2304
#define V_R2 2688
#define V_GA 3072
#define V_BE 3456

// ---------------------------------------------------------------- norms ---
__global__ __launch_bounds__(128) void k_rms1(const void* __restrict__ x,
                                              const void* __restrict__ rw,
                                              const u16* __restrict__ vecs,
                                              u16* __restrict__ h1pad) {
  const int isbf = probe_bf(rw);
  int t = blockIdx.x, tid = threadIdx.x;
  int lane = tid & 63, wid = tid >> 6;
  float v[3]; float q = 0.f;
#pragma unroll
  for (int j = 0; j < 3; ++j) {
    v[j] = ld_in(x, t * DM + tid + j * 128, isbf);
    q += v[j] * v[j];
  }
  q = wave_sum(q);
  __shared__ float rq[2];
  if (lane == 0) rq[wid] = q;
  __syncthreads();
  float rr = rsqrtf((rq[0] + rq[1]) * (1.f / DM) + 1e-6f);
  int b = t >> 11, l = t & 2047;
  size_t orow = ((size_t)(b * 2051 + l + 1)) * DM;
#pragma unroll
  for (int j = 0; j < 3; ++j) {
    int i = tid + j * 128;
    h1pad[orow + i] = f2bf(v[j] * rr * bf2f(vecs[V_R1 + i]));
  }
}

__global__ __launch_bounds__(128) void k_lnrms(const float* __restrict__ outm,
                                               const void* __restrict__ xin,
                                               const void* __restrict__ rw,
                                               const u16* __restrict__ vecs,
                                               float* __restrict__ x2f,
                                               u16* __restrict__ h2) {
  const int isbf = probe_bf(rw);
  int t = blockIdx.x, tid = threadIdx.x;
  int lane = tid & 63, wid = tid >> 6;
  float v[3]; float s = 0.f, q = 0.f;
#pragma unroll
  for (int j = 0; j < 3; ++j) {
    v[j] = outm[(size_t)t * DM + tid + j * 128];
    s += v[j]; q += v[j] * v[j];
  }
  s = wave_sum(s); q = wave_sum(q);
  __shared__ float rs[2], rq[2], r2[2];
  if (lane == 0) { rs[wid] = s; rq[wid] = q; }
  __syncthreads();
  float mu = (rs[0] + rs[1]) * (1.f / DM);
  float var = (rq[0] + rq[1]) * (1.f / DM) - mu * mu;
  float rstd = rsqrtf(var + 1e-5f);
  float x2v[3]; float q2 = 0.f;
#pragma unroll
  for (int j = 0; j < 3; ++j) {
    int i = tid + j * 128;
    float ln = (v[j] - mu) * rstd * bf2f(vecs[V_GA + i]) + bf2f(vecs[V_BE + i]);
    x2v[j] = ld_in(xin, t * DM + i, isbf) + ln;
    x2f[(size_t)t * DM + i] = x2v[j];
    q2 += x2v[j] * x2v[j];
  }
  q2 = wave_sum(q2);
  if (lane == 0) r2[wid] = q2;
  __syncthreads();
  float rr = rsqrtf((r2[0] + r2[1]) * (1.f / DM) + 1e-6f);
#pragma unroll
  for (int j = 0; j < 3; ++j) {
    int i = tid + j * 128;
    h2[(size_t)t * DM + i] = f2bf(x2v[j] * rr * bf2f(vecs[V_R2 + i]));
  }
}

// ---------------------------------------------------------------- GEMM ----
// C[M,N] = A[M,K] @ BT[N,K]^T, MTx128 tile, BK=64, mfma 16x16x32 bf16.
// Double-buffered LDS, ONE barrier per stage: stage k reads buf[s], writes
// prefetched stage k+1 into buf[s^1]. End-of-stage barrier covers both
// hazards (all reads of a buffer precede that stage's barrier).
// EPI: 2 softplus->delta(bf16)+BC(f32), 3 f32 raw ld DM,
//      5 +res -> d_out (dtype by flag), 6 Wcomb transposed write.
template <int EPI, int MT, int KDIM>
__global__ __launch_bounds__(256) void gemm_bt(
    const u16* __restrict__ A, const u16* __restrict__ BT,
    float* __restrict__ o1, float* __restrict__ o2,
    u16* __restrict__ ob1, u16* __restrict__ ob2,
    const u16* __restrict__ bias, const float* __restrict__ res,
    const void* __restrict__ fl) {
  constexpr int AFR = MT / 32;
  constexpr int STR = MT * 64 + 8192;   // u16 per LDS buffer
  __shared__ u16 smem[2 * STR];
  const int tid = threadIdx.x;
  const int lane = tid & 63, wid = tid >> 6;
  const int wm = (wid >> 1) * (MT / 2), wn = (wid & 1) << 6;
  const int fr = lane & 15, quad = lane >> 4;
  const int r0 = tid >> 2, c8 = (tid & 3) << 3;
  const int m0 = blockIdx.x * MT, n0 = blockIdx.y * 128;

  f32x4 acc[AFR][4] = {};

  const u16* BTe = (EPI == 6) ? BT + (size_t)blockIdx.z * 589824 : BT;
  const u16* gB0 = BTe + (size_t)(n0 + r0) * KDIM + c8;
  const u16* gA0 = A + (size_t)(m0 + r0) * KDIM + c8;

  short8 a00, a01, a10, a11, b00, b01, b10, b11;
  auto stage_load = [&](int kt) {
    a00 = *(const short8*)(gA0 + kt);
    a10 = *(const short8*)(gA0 + kt + 32);
    if (MT == 128) {
      a01 = *(const short8*)(gA0 + kt + (size_t)64 * KDIM);
      a11 = *(const short8*)(gA0 + kt + 32 + (size_t)64 * KDIM);
    }
    b00 = *(const short8*)(gB0 + kt);
    b01 = *(const short8*)(gB0 + kt + (size_t)64 * KDIM);
    b10 = *(const short8*)(gB0 + kt + 32);
    b11 = *(const short8*)(gB0 + kt + 32 + (size_t)64 * KDIM);
  };
  auto wrbuf = [&](int s) {
    u16* sm = &smem[s * STR];
    *(short8*)&sm[SWZ_W(tid)] = a00;
    if (MT == 128) *(short8*)&sm[2048 + SWZ_W(tid)] = a01;
    *(short8*)&sm[MT * 32 + SWZ_W(tid)] = a10;
    if (MT == 128) *(short8*)&sm[MT * 32 + 2048 + SWZ_W(tid)] = a11;
    *(short8*)&sm[MT * 64 + SWZ_W(tid)]        = b00;
    *(short8*)&sm[MT * 64 + 2048 + SWZ_W(tid)] = b01;
    *(short8*)&sm[MT * 64 + 4096 + SWZ_W(tid)] = b10;
    *(short8*)&sm[MT * 64 + 6144 + SWZ_W(tid)] = b11;
  };

  stage_load(0);
  wrbuf(0);
  __syncthreads();
  int sbuf = 0;

#pragma unroll 1
  for (int kt = 0; kt < KDIM; kt += 64) {
    const bool more = (kt + 64 < KDIM);
    if (more) stage_load(kt + 64);
    const u16* sm = &smem[sbuf * STR];
#pragma unroll
    for (int kh = 0; kh < 2; ++kh) {
      const int ao = kh * MT * 32, bo = MT * 64 + kh * 4096;
      short8 af[AFR], bfg[4];
#pragma unroll
      for (int i = 0; i < AFR; ++i)
        af[i] = *(const short8*)&sm[ao + SWZ_R(wm + i * 16 + fr, quad)];
#pragma unroll
      for (int i = 0; i < 4; ++i)
        bfg[i] = *(const short8*)&sm[bo + SWZ_R(wn + i * 16 + fr, quad)];
#pragma unroll
      for (int mt = 0; mt < AFR; ++mt)
#pragma unroll
        for (int nt = 0; nt < 4; ++nt)
          acc[mt][nt] = __builtin_amdgcn_mfma_f32_16x16x32_bf16(
              af[mt], bfg[nt], acc[mt][nt], 0, 0, 0);
    }
    if (more) {
      wrbuf(sbuf ^ 1);
      sbuf ^= 1;
      __syncthreads();
    }
  }

  int isbf = 0;
  if (EPI == 5) isbf = probe_bf(fl);

#pragma unroll
  for (int mt = 0; mt < AFR; ++mt) {
#pragma unroll
    for (int nt = 0; nt < 4; ++nt) {
#pragma unroll
      for (int r = 0; r < 4; ++r) {
        int t = m0 + wm + mt * 16 + quad * 4 + r;
        int n = n0 + wn + nt * 16 + fr;
        float v = acc[mt][nt][r];
        if (EPI == 2) {  // delta bf16 ; BC raw f32
          if (n < DI) {
            float xx = v + bf2f(bias[n]);
            float sp = (xx > 20.f) ? xx : log1pf(__expf(xx));
            ob1[(size_t)t * DI + n] = f2bf(sp);
          } else if (n < DI + 32) {
            o2[(size_t)t * 32 + (n - DI)] = v;
          }
        } else if (EPI == 3) {
          o1[(size_t)t * DM + n] = v;
        } else if (EPI == 5) {
          float val = v + res[(size_t)t * DM + n];
          if (isbf) ob1[(size_t)t * DM + n] = f2bf(val);
          else      o1[(size_t)t * DM + n] = val;
        } else if (EPI == 6) {
          ob1[(size_t)n * 1536 + blockIdx.z * 384 + t] = f2bf(v);
        }
      }
    }
  }
}

// Merged z + conv GEMM, MT=64, BK=64, double-buffered single-barrier LDS.
// blockIdx.y < 6: xconv = silu(sum_tap h1[l-1+tap] @ Wcomb[tap] + b), K=1536
// blockIdx.y >= 6: zbuf = h1[l] @ Win_z, K=384 (rowoff 1).
__global__ __launch_bounds__(256) void gemm_xz(
    const u16* __restrict__ A, const u16* __restrict__ WC,
    const u16* __restrict__ WZ, u16* __restrict__ xconv,
    u16* __restrict__ zbuf, const u16* __restrict__ bias) {
  constexpr int STR = 12288;  // u16 per buffer: A0/A1 @0/2048, B @4096..12288
  __shared__ u16 smem[2 * STR];
  const int tid = threadIdx.x;
  const int lane = tid & 63, wid = tid >> 6;
  const int wm = (wid >> 1) << 5, wn = (wid & 1) << 6;
  const int fr = lane & 15, quad = lane >> 4;
  const int r0 = tid >> 2, c8 = (tid & 3) << 3;
  const int yb = blockIdx.y;
  const bool isz = yb >= 6;
  const int kd = isz ? 384 : 1536;
  const u16* BT = isz ? WZ : WC;
  const int kldb = isz ? 384 : 1536;
  const int n0 = (isz ? yb - 6 : yb) * 128;
  const int m0 = blockIdx.x * 64;

  f32x4 acc[2][4] = {};

  const u16* gB0 = BT + (size_t)(n0 + r0) * kldb + c8;
  const int b = m0 >> 11, l0 = m0 & 2047;
  const u16* gA0 = A + (size_t)(b * 2051 + l0 + r0 + (isz ? 1 : 0)) * DM + c8;

  short8 a0, a1, b00, b01, b10, b11;
  int wconv = 0, i0 = 0;
  auto calcA = [&]() -> const u16* {
    const u16* p = gA0 + (size_t)wconv * DM + i0;
    i0 += 32;
    if (i0 == DM) { i0 = 0; ++wconv; }
    return p;
  };
  auto stage_load = [&](int kt) {
    a0 = *(const short8*)calcA();
    a1 = *(const short8*)calcA();
    b00 = *(const short8*)(gB0 + kt);
    b01 = *(const short8*)(gB0 + kt + (size_t)64 * kldb);
    b10 = *(const short8*)(gB0 + kt + 32);
    b11 = *(const short8*)(gB0 + kt + 32 + (size_t)64 * kldb);
  };
  auto wrbuf = [&](int s) {
    u16* sm = &smem[s * STR];
    *(short8*)&sm[SWZ_W(tid)]         = a0;
    *(short8*)&sm[2048 + SWZ_W(tid)]  = a1;
    *(short8*)&sm[4096 + SWZ_W(tid)]  = b00;
    *(short8*)&sm[6144 + SWZ_W(tid)]  = b01;
    *(short8*)&sm[8192 + SWZ_W(tid)]  = b10;
    *(short8*)&sm[10240 + SWZ_W(tid)] = b11;
  };

  stage_load(0);
  wrbuf(0);
  __syncthreads();
  int sbuf = 0;

#pragma unroll 1
  for (int kt = 0; kt < kd; kt += 64) {
    const bool more = (kt + 64 < kd);
    if (more) stage_load(kt + 64);
    const u16* sm = &smem[sbuf * STR];
#pragma unroll
    for (int kh = 0; kh < 2; ++kh) {
      const int ao = kh * 2048, bo = 4096 + kh * 4096;
      short8 af[2], bfg[4];
#pragma unroll
      for (int i = 0; i < 2; ++i)
        af[i] = *(const short8*)&sm[ao + SWZ_R(wm + i * 16 + fr, quad)];
#pragma unroll
      for (int i = 0; i < 4; ++i)
        bfg[i] = *(const short8*)&sm[bo + SWZ_R(wn + i * 16 + fr, quad)];
#pragma unroll
      for (int mt = 0; mt < 2; ++mt)
#pragma unroll
        for (int nt = 0; nt < 4; ++nt)
          acc[mt][nt] = __builtin_amdgcn_mfma_f32_16x16x32_bf16(
              af[mt], bfg[nt], acc[mt][nt], 0, 0, 0);
    }
    if (more) {
      wrbuf(sbuf ^ 1);
      sbuf ^= 1;
      __syncthreads();
    }
  }

#pragma unroll
  for (int mt = 0; mt < 2; ++mt) {
#pragma unroll
    for (int nt = 0; nt < 4; ++nt) {
#pragma unroll
      for (int r = 0; r < 4; ++r) {
        int t = m0 + wm + mt * 16 + quad * 4 + r;
        int n = n0 + wn + nt * 16 + fr;
        float v = acc[mt][nt][r];
        if (isz) {
          zbuf[(size_t)t * DI + n] = f2bf(v);
        } else {
          float xx = v + bf2f(bias[n]);
          float sg = 1.f / (1.f + __expf(-xx));
          xconv[(size_t)t * DI + n] = f2bf(xx * sg);
        }
      }
    }
  }
}

// Fused FFN gate|up GEMM + GLU, MT=64, BK=64, single-buffered (dbuf would
// exceed the 64KB static LDS limit), swizzled.
__global__ __launch_bounds__(256) void gemm_gu(
    const u16* __restrict__ A, const u16* __restrict__ W6T,
    u16* __restrict__ hid) {
  __shared__ u16 smem[20480];
  const int tid = threadIdx.x;
  const int lane = tid & 63, wid = tid >> 6;
  const int wm = (wid >> 1) << 5, wn = (wid & 1) << 6;
  const int fr = lane & 15, quad = lane >> 4;
  const int r0 = tid >> 2, c8 = (tid & 3) << 3;
  const int m0 = blockIdx.x * 64, n0 = blockIdx.y * 128;

  f32x4 accg[2][4] = {}, accu[2][4] = {};

  const u16* gA0 = A + (size_t)(m0 + r0) * DM + c8;
  const u16* gG0 = W6T + (size_t)(n0 + r0) * DM + c8;
  const u16* gU0 = W6T + (size_t)(1024 + n0 + r0) * DM + c8;

  short8 a0, a1, g00, g01, g10, g11, u00, u01, u10, u11;
  auto stage_load = [&](int kt) {
    a0  = *(const short8*)(gA0 + kt);
    a1  = *(const short8*)(gA0 + kt + 32);
    g00 = *(const short8*)(gG0 + kt);
    g01 = *(const short8*)(gG0 + kt + (size_t)64 * DM);
    g10 = *(const short8*)(gG0 + kt + 32);
    g11 = *(const short8*)(gG0 + kt + 32 + (size_t)64 * DM);
    u00 = *(const short8*)(gU0 + kt);
    u01 = *(const short8*)(gU0 + kt + (size_t)64 * DM);
    u10 = *(const short8*)(gU0 + kt + 32);
    u11 = *(const short8*)(gU0 + kt + 32 + (size_t)64 * DM);
  };

  stage_load(0);

#pragma unroll 1
  for (int kt = 0; kt < DM; kt += 64) {
    __syncthreads();
    *(short8*)&smem[SWZ_W(tid)]          = a0;
    *(short8*)&smem[2048 + SWZ_W(tid)]   = a1;
    *(short8*)&smem[4096 + SWZ_W(tid)]   = g00;
    *(short8*)&smem[6144 + SWZ_W(tid)]   = g01;
    *(short8*)&smem[8192 + SWZ_W(tid)]   = g10;
    *(short8*)&smem[10240 + SWZ_W(tid)]  = g11;
    *(short8*)&smem[12288 + SWZ_W(tid)]  = u00;
    *(short8*)&smem[14336 + SWZ_W(tid)]  = u01;
    *(short8*)&smem[16384 + SWZ_W(tid)]  = u10;
    *(short8*)&smem[18432 + SWZ_W(tid)]  = u11;
    __syncthreads();
    if (kt + 64 < DM) stage_load(kt + 64);
#pragma unroll
    for (int kh = 0; kh < 2; ++kh) {
      const int ao = kh * 2048, go = 4096 + kh * 4096, uo = 12288 + kh * 4096;
      short8 af[2], bg[4], bu[4];
#pragma unroll
      for (int i = 0; i < 2; ++i)
        af[i] = *(const short8*)&smem[ao + SWZ_R(wm + i * 16 + fr, quad)];
#pragma unroll
      for (int i = 0; i < 4; ++i) {
        bg[i] = *(const short8*)&smem[go + SWZ_R(wn + i * 16 + fr, quad)];
        bu[i] = *(const short8*)&smem[uo + SWZ_R(wn + i * 16 + fr, quad)];
      }
#pragma unroll
      for (int mt = 0; mt < 2; ++mt)
#pragma unroll
        for (int nt = 0; nt < 4; ++nt) {
          accg[mt][nt] = __builtin_amdgcn_mfma_f32_16x16x32_bf16(
              af[mt], bg[nt], accg[mt][nt], 0, 0, 0);
          accu[mt][nt] = __builtin_amdgcn_mfma_f32_16x16x32_bf16(
              af[mt], bu[nt], accu[mt][nt], 0, 0, 0);
        }
    }
  }

#pragma unroll
  for (int mt = 0; mt < 2; ++mt) {
#pragma unroll
    for (int nt = 0; nt < 4; ++nt) {
#pragma unroll
      for (int r = 0; r < 4; ++r) {
        int t = m0 + wm + mt * 16 + quad * 4 + r;
        int n = n0 + wn + nt * 16 + fr;
        float g = accg[mt][nt][r];
        float u = accu[mt][nt][r];
        float sg = 1.f / (1.f + __expf(-g));
        hid[(size_t)t * 1024 + n] = f2bf(g * sg * u);
      }
    }
  }
}

// ---------------------------------------------------------------- scan ----
// Fat threads: 16 states/thread, NCH=64 chunks of 32, next-row prefetch.
__global__ __launch_bounds__(256) void k_scan1(
    const u16* __restrict__ deltab, const u16* __restrict__ xconv,
    const float* __restrict__ BC, const float* __restrict__ An2T,
    float* __restrict__ hlb, float* __restrict__ Pb) {
  int gid = blockIdx.x * 256 + threadIdx.x;
  int d = gid % DI, bc = gid / DI, c = bc & (NCH - 1), b = bc >> 6;
  float An[NST];
#pragma unroll
  for (int n = 0; n < NST; ++n) An[n] = An2T[n * DI + d];
  float h[NST], P[NST];
#pragma unroll
  for (int n = 0; n < NST; ++n) { h[n] = 0.f; P[n] = 1.f; }
  int row0 = b * LSEQ + c * LCH;
  float dt = bf2f(deltab[(size_t)row0 * DI + d]);
  float xv = bf2f(xconv[(size_t)row0 * DI + d]);
  float4 q[4];
  {
    const float4* q4 = (const float4*)(BC + (size_t)row0 * 32);
#pragma unroll
    for (int i = 0; i < 4; ++i) q[i] = q4[i];
  }
  for (int s = 0; s < LCH; ++s) {
    float dtc = dt, xvc = xv;
    float Bm[NST];
#pragma unroll
    for (int i = 0; i < 4; ++i) {
      Bm[4*i] = q[i].x; Bm[4*i+1] = q[i].y;
      Bm[4*i+2] = q[i].z; Bm[4*i+3] = q[i].w;
    }
    if (s + 1 < LCH) {
      int r2 = row0 + s + 1;
      dt = bf2f(deltab[(size_t)r2 * DI + d]);
      xv = bf2f(xconv[(size_t)r2 * DI + d]);
      const float4* q4 = (const float4*)(BC + (size_t)r2 * 32);
#pragma unroll
      for (int i = 0; i < 4; ++i) q[i] = q4[i];
    }
    float dxv = dtc * xvc;
#pragma unroll
    for (int n = 0; n < NST; ++n) {
      float a = fexp2(dtc * An[n]);
      h[n] = fmaf(a, h[n], dxv * Bm[n]);
      P[n] *= a;
    }
  }
  float4* ph = (float4*)(hlb + (size_t)gid * NST);
  float4* pp = (float4*)(Pb + (size_t)gid * NST);
#pragma unroll
  for (int i = 0; i < 4; ++i) {
    ph[i] = make_float4(h[4*i], h[4*i+1], h[4*i+2], h[4*i+3]);
    pp[i] = make_float4(P[4*i], P[4*i+1], P[4*i+2], P[4*i+3]);
  }
}

__global__ __launch_bounds__(256) void k_scan2(const float* __restrict__ hlb,
                                               const float* __restrict__ Pb,
                                               float* __restrict__ hin) {
  int gid = blockIdx.x * 256 + threadIdx.x;  // (b*DI+d)*16+n
  int n = gid & 15, bd = gid >> 4;
  int d = bd % DI, b = bd / DI;
  float H = 0.f;
  for (int c = 0; c < NCH; ++c) {
    size_t idx = ((size_t)((b * NCH + c) * DI + d)) * NST + n;
    hin[idx] = H;
    H = hlb[idx] + Pb[idx] * H;
  }
}

__global__ __launch_bounds__(256) void k_scan3(
    const u16* __restrict__ deltab, const u16* __restrict__ xconv,
    const float* __restrict__ BC, const float* __restrict__ An2T,
    const float* __restrict__ hinb, const u16* __restrict__ zb,
    const u16* __restrict__ vecs, u16* __restrict__ ys) {
  int gid = blockIdx.x * 256 + threadIdx.x;
  int d = gid % DI, bc = gid / DI, c = bc & (NCH - 1), b = bc >> 6;
  float An[NST];
#pragma unroll
  for (int n = 0; n < NST; ++n) An[n] = An2T[n * DI + d];
  float h[NST];
  {
    const float4* hp = (const float4*)(hinb + (size_t)gid * NST);
#pragma unroll
    for (int i = 0; i < 4; ++i) {
      float4 t = hp[i];
      h[4*i] = t.x; h[4*i+1] = t.y; h[4*i+2] = t.z; h[4*i+3] = t.w;
    }
  }
  float Dd = bf2f(vecs[V_DP + d]);
  int row0 = b * LSEQ + c * LCH;
  float dt = bf2f(deltab[(size_t)row0 * DI + d]);
  float xv = bf2f(xconv[(size_t)row0 * DI + d]);
  float zv = bf2f(zb[(size_t)row0 * DI + d]);
  float4 q[8];
  {
    const float4* q4 = (const float4*)(BC + (size_t)row0 * 32);
#pragma unroll
    for (int i = 0; i < 8; ++i) q[i] = q4[i];
  }
  for (int s = 0; s < LCH; ++s) {
    int row = row0 + s;
    float dtc = dt, xvc = xv, zvc = zv;
    float Bm[NST], Cm[NST];
#pragma unroll
    for (int i = 0; i < 4; ++i) {
      Bm[4*i] = q[i].x;   Bm[4*i+1] = q[i].y;
      Bm[4*i+2] = q[i].z; Bm[4*i+3] = q[i].w;
      Cm[4*i] = q[4+i].x;   Cm[4*i+1] = q[4+i].y;
      Cm[4*i+2] = q[4+i].z; Cm[4*i+3] = q[4+i].w;
    }
    if (s + 1 < LCH) {
      int r2 = row + 1;
      dt = bf2f(deltab[(size_t)r2 * DI + d]);
      xv = bf2f(xconv[(size_t)r2 * DI + d]);
      zv = bf2f(zb[(size_t)r2 * DI + d]);
      const float4* q4 = (const float4*)(BC + (size_t)r2 * 32);
#pragma unroll
      for (int i = 0; i < 8; ++i) q[i] = q4[i];
    }
    float dxv = dtc * xvc;
    float yp[4] = {0.f, 0.f, 0.f, 0.f};
#pragma unroll
    for (int n = 0; n < NST; ++n) {
      float a = fexp2(dtc * An[n]);
      h[n] = fmaf(a, h[n], dxv * Bm[n]);
      yp[n & 3] = fmaf(h[n], Cm[n], yp[n & 3]);
    }
    float y = (yp[0] + yp[1]) + (yp[2] + yp[3]);
    float sz = zvc / (1.f + __expf(-zvc));
    ys[(size_t)row * DI + d] = f2bf((y + Dd * xvc) * sz);
  }
}

// ---------------------------------------------------------------- host ----
extern "C" void kernel_launch(void* const* d_in, const int* in_sizes, int n_in,
                              void* d_out, int out_size, void* d_ws,
                              size_t ws_size, hipStream_t stream) {
  (void)in_sizes; (void)n_in; (void)out_size;
  const void* x        = d_in[0];
  const void* rms1_w   = d_in[1];
  const void* rms2_w   = d_in[2];
  const void* in_proj  = d_in[3];
  const void* conv_w   = d_in[4];
  const void* conv_b   = d_in[5];
  const void* x_proj   = d_in[6];
  const void* dt_w     = d_in[7];
  const void* dt_b     = d_in[8];
  const void* A_log    = d_in[9];
  const void* Dp       = d_in[10];
  const void* out_proj = d_in[11];
  const void* gamma    = d_in[12];
  const void* beta     = d_in[13];
  const void* gate_w   = d_in[14];
  const void* up_w     = d_in[15];
  const void* down_w   = d_in[16];

  char* ws = (char*)d_ws;
  size_t off = 0;
  auto alloc = [&](size_t bytes) -> void* {
    void* p = ws + off;
    off = (off + bytes + 255) & ~(size_t)255;
    return p;
  };
  // weights (persistent), bf16 [N][K]
  u16*   W1T   = (u16*)alloc((size_t)1536 * 384 * 2);
  u16*   WCT   = (u16*)alloc((size_t)4 * 768 * 768 * 2);
  u16*   W45T  = (u16*)alloc((size_t)896 * 768 * 2);
  u16*   W5T   = (u16*)alloc((size_t)384 * 768 * 2);
  u16*   W6T   = (u16*)alloc((size_t)2048 * 384 * 2);
  u16*   W7T   = (u16*)alloc((size_t)384 * 1024 * 2);
  float* An2T  = (float*)alloc((size_t)16 * 768 * 4);
  u16*   vecs  = (u16*)alloc(3840 * 2);
  u16*   WinX  = (u16*)alloc((size_t)384 * 768 * 2);
  u16*   WcombT= (u16*)alloc((size_t)768 * 1536 * 2);
  // activations
  u16*   h1pad = (u16*)alloc((size_t)4 * 2051 * 384 * 2);  // rms1 -> gemm_xz
  u16*   zbuf  = (u16*)alloc((size_t)8192 * 768 * 2);      // gemm_xz -> scan3
  u16*   xconv = (u16*)alloc((size_t)8192 * 768 * 2);      // gemm_xz -> scan3
  u16*   deltab= (u16*)alloc((size_t)8192 * 768 * 2);      // gemm2 -> scan3
  float* BCb   = (float*)alloc((size_t)8192 * 32 * 4);     // gemm2 -> scan3
  float* hl    = (float*)alloc((size_t)196608 * 16 * 4);   // scan1 -> scan2
  float* Pb    = (float*)alloc((size_t)196608 * 16 * 4);   // scan1 -> scan2
  float* hin   = (float*)alloc((size_t)196608 * 16 * 4);   // scan2 -> scan3
  // ~96 MB total.  Aliases (write begins after host region's last read):
  u16*   ys   = (u16*)hl;     // scan3 -> gemm3  (hl dead after scan2)
  float* outm = Pb;           // gemm3 -> lnrms  (Pb dead after scan2)
  float* x2f  = hin;          // lnrms -> gemm5  (hin dead after scan3)
  u16*   h2   = h1pad;        // lnrms -> gemm_gu (h1pad dead after gemm_xz)
  u16*   hid  = (u16*)hl;     // gemm_gu -> gemm5 (ys dead after gemm3,
                              //   Pb=outm dead after lnrms; spans both)

  if (off > ws_size) return;  // ws-too-small signal: absmax == max|ref|

  k_prep<<<20913, 256, 0, stream>>>(
      in_proj, conv_w, dt_w, x_proj, out_proj, gate_w, up_w, down_w, A_log,
      conv_b, dt_b, Dp, rms1_w, rms2_w, gamma, beta,
      W1T, WCT, W45T, W5T, W6T, W7T, An2T, vecs, WinX, h1pad);

  // Wcomb[tap] = Win_x @ Wc[tap] -> WcombT [768][4*384]
  gemm_bt<6, 128, 768><<<dim3(3, 6, 4), 256, 0, stream>>>(
      WinX, WCT, nullptr, nullptr, WcombT, nullptr, nullptr, nullptr, nullptr);

  k_rms1<<<8192, 128, 0, stream>>>(x, rms1_w, vecs, h1pad);

  // merged MT=64: y<6 -> xconv (K=1536, silu) ; y>=6 -> zbuf (K=384)
  gemm_xz<<<dim3(128, 12), 256, 0, stream>>>(
      h1pad, WcombT, W1T + (size_t)768 * 384, xconv, zbuf, vecs + V_CB);

  // delta = softplus(x_conv@dt_w + b) (bf16) ; BC = x_conv@x_proj (f32)
  gemm_bt<2, 64, 768><<<dim3(128, 7), 256, 0, stream>>>(
      xconv, W45T, nullptr, BCb, deltab, nullptr, vecs + V_DB, nullptr,
      nullptr);

  k_scan1<<<768, 256, 0, stream>>>(deltab, xconv, BCb, An2T, hl, Pb);
  k_scan2<<<192, 256, 0, stream>>>(hl, Pb, hin);
  k_scan3<<<768, 256, 0, stream>>>(deltab, xconv, BCb, An2T, hin, zbuf, vecs,
                                   ys);

  // out = ys @ out_proj (f32)
  gemm_bt<3, 64, 768><<<dim3(128, 3), 256, 0, stream>>>(
      ys, W5T, outm, nullptr, nullptr, nullptr, nullptr, nullptr, nullptr);
  k_lnrms<<<8192, 128, 0, stream>>>(outm, x, rms1_w, vecs, x2f, h2);

  // fused gate|up GEMM + GLU -> hid ; down + residual -> out
  gemm_gu<<<dim3(128, 8), 256, 0, stream>>>(h2, W6T, hid);
  gemm_bt<5, 64, 1024><<<dim3(128, 3), 256, 0, stream>>>(
      hid, W7T, (float*)d_out, nullptr, (u16*)d_out, nullptr, nullptr, x2f,
      rms1_w);
}

// Round 15
// 334.978 us; speedup vs baseline: 1.0895x; 1.0895x over previous
//
#include <hip/hip_runtime.h>
#include <hip/hip_bf16.h>

// ImprovedCobrablock on MI355X (gfx950).
// Inputs/output f32 (verified r3). bf16 MFMA GEMMs, f32 scan state.
// GEMM: register staging + prefetch (r5), BK=64 (r11), XOR swizzle (r12).
// r13 dbuf REVERTED (regressed). Conv folded into Wcomb (r7). Fat-thread
// scan NCH=64 (r8). MT=64 + z/conv merge (r9). gemm_gu fusion (r10).
// r15 = r14 with the WinX block-range overflow FIXED (was 2304 blocks for a
// 1152-block range -> OOB reads of in_proj -> device fault):
// k_prep: LDS-tiled transposes (coalesced both sides) + rms1 folded in.
// B=4, L=2048, D=384, Di=768, N=16, K=4, FFN=1024, T=8192.

using u16 = unsigned short;
using u32 = unsigned int;
using short8 = __attribute__((ext_vector_type(8))) short;
using f32x4  = __attribute__((ext_vector_type(4))) float;

#define TTOK 8192
#define DM 384
#define DI 768
#define NST 16
#define LSEQ 2048
#define NCH 64   /* chunks per sequence */
#define LCH 32   /* chunk length */

// LDS tile layout: [rows][32 u16], 4 chunks of 8 u16 per row, XOR-swizzled.
#define SWZ_R(row, quad) \
  ((row) * 32 + ((((quad) ^ (row) ^ ((row) >> 2)) & 3) * 8))
#define SWZ_W(tid) SWZ_R((tid) >> 2, (tid) & 3)

__device__ __forceinline__ float bf2f(u16 a) {
  u32 u = ((u32)a) << 16;
  float f; __builtin_memcpy(&f, &u, 4); return f;
}
__device__ __forceinline__ u16 f2bf(float f) {
  u32 u; __builtin_memcpy(&u, &f, 4);
  u32 r = (u + 0x7fffu + ((u >> 16) & 1u)) >> 16;  // RNE
  return (u16)r;
}
__device__ __forceinline__ int probe_bf(const void* rw) {
  return (((const u32*)rw)[0] == 0x3F803F80u) ? 1 : 0;
}
__device__ __forceinline__ float ld_in(const void* p, int i, int isbf) {
  return isbf ? bf2f(((const u16*)p)[i]) : ((const float*)p)[i];
}
__device__ __forceinline__ float fexp2(float x) {
#if __has_builtin(__builtin_amdgcn_exp2f)
  return __builtin_amdgcn_exp2f(x);
#else
  return exp2f(x);
#endif
}
__device__ __forceinline__ float wave_sum(float v) {
#pragma unroll
  for (int off = 32; off > 0; off >>= 1) v += __shfl_xor(v, off, 64);
  return v;
}

// vecs[] layout offsets
#define V_CB 0
#define V_DB 768
#define V_DP 1536
#define V_R1 2304
#define V_R2 2688
#define V_GA 3072
#define V_BE 3456

// ---------------------------------------------------------------- prep ----
// One dispatch, block ranges:
// [0,1236): 64x64 LDS-tiled transposes (coalesced loads AND stores)
// [1236,5332): rms1 (2 tokens/block) -> h1pad interior rows
// [5332,6484): WinX copy (294912 elems = 1152 blocks exactly)
// [6484,6532): A_log->An2T   [6532,6547): vecs   [6547,6565): halo zero
__global__ __launch_bounds__(256) void k_prep(
    const void* __restrict__ x, const void* __restrict__ in_proj,
    const void* __restrict__ conv_w, const void* __restrict__ dt_w,
    const void* __restrict__ x_proj, const void* __restrict__ out_proj,
    const void* __restrict__ gate_w, const void* __restrict__ up_w,
    const void* __restrict__ down_w, const void* __restrict__ A_log,
    const void* __restrict__ conv_b, const void* __restrict__ dt_b,
    const void* __restrict__ Dp, const void* __restrict__ rms1_w,
    const void* __restrict__ rms2_w, const void* __restrict__ gamma,
    const void* __restrict__ beta,
    u16* __restrict__ W1T, u16* __restrict__ WCT, u16* __restrict__ W45T,
    u16* __restrict__ W5T, u16* __restrict__ W6T, u16* __restrict__ W7T,
    float* __restrict__ An2T, u16* __restrict__ vecs,
    u16* __restrict__ WinX, u16* __restrict__ h1pad) {
  const int isbf = probe_bf(rms1_w);
  const int bx = blockIdx.x;
  const int tid = threadIdx.x;
  __shared__ u16 lt[64 * 66];  // stride 66 u16 = 33 dwords -> <=2-way banks

  if (bx < 1236) {  // tiled transpose: dst[c][r] = src[r][c]
    const void* src; size_t soff = 0; u16* dst; int R, C, tpr, lo;
    if (bx < 144)       { src = in_proj;  dst = W1T;  R = 384;  C = 1536; tpr = 24; lo = bx; }
    else if (bx < 720)  { int tp = (bx - 144) / 144; lo = (bx - 144) % 144;
                          src = conv_w; soff = (size_t)tp * 589824;
                          dst = WCT + (size_t)tp * 589824; R = 768; C = 768; tpr = 12; }
    else if (bx < 864)  { src = dt_w;     dst = W45T; R = 768;  C = 768;  tpr = 12; lo = bx - 720; }
    else if (bx < 876)  { src = x_proj;   dst = W45T + (size_t)768 * 768;
                          R = 768; C = 32; tpr = 1; lo = bx - 864; }
    else if (bx < 948)  { src = out_proj; dst = W5T;  R = 768;  C = 384;  tpr = 6;  lo = bx - 876; }
    else if (bx < 1044) { src = gate_w;   dst = W6T;  R = 384;  C = 1024; tpr = 16; lo = bx - 948; }
    else if (bx < 1140) { src = up_w;     dst = W6T + (size_t)1024 * 384;
                          R = 384; C = 1024; tpr = 16; lo = bx - 1044; }
    else                { src = down_w;   dst = W7T;  R = 1024; C = 384;  tpr = 6;  lo = bx - 1140; }
    int tr = lo / tpr, tc = lo % tpr;
    int r0 = tr * 64, c0 = tc * 64;
#pragma unroll
    for (int i = 0; i < 16; ++i) {
      int el = i * 256 + tid, lr = el >> 6, lc = el & 63;
      if (c0 + lc < C)
        lt[lr * 66 + lc] =
            f2bf(ld_in(src, (int)(soff + (size_t)(r0 + lr) * C + c0 + lc), isbf));
    }
    __syncthreads();
#pragma unroll
    for (int i = 0; i < 16; ++i) {
      int el = i * 256 + tid, orow = el >> 6, oc = el & 63;
      if (c0 + orow < C)
        dst[(size_t)(c0 + orow) * R + r0 + oc] = lt[oc * 66 + orow];
    }
    return;
  }
  if (bx < 5332) {  // rms1: 2 tokens per block (waves 0-1 / 2-3)
    int half = tid >> 7;
    int t = (bx - 1236) * 2 + half;
    int tid2 = tid & 127;
    int lane = tid & 63, wv = tid >> 6;
    float v[3]; float q = 0.f;
#pragma unroll
    for (int j = 0; j < 3; ++j) {
      v[j] = ld_in(x, t * DM + tid2 + j * 128, isbf);
      q += v[j] * v[j];
    }
    q = wave_sum(q);
    float* rq = (float*)lt;
    if (lane == 0) rq[wv] = q;
    __syncthreads();
    float rr = rsqrtf((rq[half * 2] + rq[half * 2 + 1]) * (1.f / DM) + 1e-6f);
    int b = t >> 11, l = t & 2047;
    size_t orow = ((size_t)(b * 2051 + l + 1)) * DM;
#pragma unroll
    for (int j = 0; j < 3; ++j) {
      int i = tid2 + j * 128;
      h1pad[orow + i] = f2bf(v[j] * rr * ld_in(rms1_w, i, isbf));
    }
    return;
  }
  if (bx < 6484) {  // WinX = in_proj[:, 0:768] as [384][768] bf16
    int lo = (bx - 5332) * 256 + tid;  // < 294912 exactly
    int i = lo / 768, j = lo % 768;
    WinX[lo] = f2bf(ld_in(in_proj, i * 1536 + j, isbf));
    return;
  }
  if (bx < 6532) {  // A_log [768][16] -> An2T [16][768] = -exp * log2e
    int lo = (bx - 6484) * 256 + tid;
    if (lo < 12288) {
      int d = lo >> 4, n = lo & 15;
      An2T[n * DI + d] = -__expf(ld_in(A_log, lo, isbf)) * 1.44269504f;
    }
    return;
  }
  if (bx < 6547) {  // small vectors -> bf16 vecs[]
    int lo = (bx - 6532) * 256 + tid;
    if (lo < 3840) {
      const void* s; int o;
      if      (lo < 768)  { s = conv_b; o = lo; }
      else if (lo < 1536) { s = dt_b;   o = lo - 768; }
      else if (lo < 2304) { s = Dp;     o = lo - 1536; }
      else if (lo < 2688) { s = rms1_w; o = lo - 2304; }
      else if (lo < 3072) { s = rms2_w; o = lo - 2688; }
      else if (lo < 3456) { s = gamma;  o = lo - 3072; }
      else                { s = beta;   o = lo - 3456; }
      vecs[lo] = f2bf(ld_in(s, o, isbf));
    }
    return;
  }
  {  // h1pad halo rows 0, 2049, 2050 per batch -> 0
    int lo = (bx - 6547) * 256 + tid;
    if (lo < 4608) {
      int b = lo / (3 * DM), rem = lo % (3 * DM);
      int which = rem / DM, i = rem % DM;
      int row = b * 2051 + (which == 0 ? 0 : (2048 + which));
      h1pad[(size_t)row * DM + i] = 0;
    }
  }
}

// ---------------------------------------------------------------- norms ---
__global__ __launch_bounds__(128) void k_lnrms(const float* __restrict__ outm,
                                               const void* __restrict__ xin,
                                               const void* __restrict__ rw,
                                               const u16* __restrict__ vecs,
                                               float* __restrict__ x2f,
                                               u16* __restrict__ h2) {
  const int isbf = probe_bf(rw);
  int t = blockIdx.x, tid = threadIdx.x;
  int lane = tid & 63, wid = tid >> 6;
  float v[3]; float s = 0.f, q = 0.f;
#pragma unroll
  for (int j = 0; j < 3; ++j) {
    v[j] = outm[(size_t)t * DM + tid + j * 128];
    s += v[j]; q += v[j] * v[j];
  }
  s = wave_sum(s); q = wave_sum(q);
  __shared__ float rs[2], rq[2], r2[2];
  if (lane == 0) { rs[wid] = s; rq[wid] = q; }
  __syncthreads();
  float mu = (rs[0] + rs[1]) * (1.f / DM);
  float var = (rq[0] + rq[1]) * (1.f / DM) - mu * mu;
  float rstd = rsqrtf(var + 1e-5f);
  float x2v[3]; float q2 = 0.f;
#pragma unroll
  for (int j = 0; j < 3; ++j) {
    int i = tid + j * 128;
    float ln = (v[j] - mu) * rstd * bf2f(vecs[V_GA + i]) + bf2f(vecs[V_BE + i]);
    x2v[j] = ld_in(xin, t * DM + i, isbf) + ln;
    x2f[(size_t)t * DM + i] = x2v[j];
    q2 += x2v[j] * x2v[j];
  }
  q2 = wave_sum(q2);
  if (lane == 0) r2[wid] = q2;
  __syncthreads();
  float rr = rsqrtf((r2[0] + r2[1]) * (1.f / DM) + 1e-6f);
#pragma unroll
  for (int j = 0; j < 3; ++j) {
    int i = tid + j * 128;
    h2[(size_t)t * DM + i] = f2bf(x2v[j] * rr * bf2f(vecs[V_R2 + i]));
  }
}

// ---------------------------------------------------------------- GEMM ----
// C[M,N] = A[M,K] @ BT[N,K]^T, MTx128 tile, BK=64, mfma 16x16x32 bf16,
// register staging + next-stage prefetch, XOR-swizzled single-buffer LDS
// (r12-verified structure).
// EPI: 2 softplus->delta(bf16)+BC(f32), 3 f32 raw ld DM,
//      5 +res -> d_out (dtype by flag), 6 Wcomb transposed write.
template <int EPI, int MT, int KDIM>
__global__ __launch_bounds__(256) void gemm_bt(
    const u16* __restrict__ A, const u16* __restrict__ BT,
    float* __restrict__ o1, float* __restrict__ o2,
    u16* __restrict__ ob1, u16* __restrict__ ob2,
    const u16* __restrict__ bias, const float* __restrict__ res,
    const void* __restrict__ fl) {
  constexpr int AFR = MT / 32;
  __shared__ u16 smem[MT * 64 + 8192];
  const int tid = threadIdx.x;
  const int lane = tid & 63, wid = tid >> 6;
  const int wm = (wid >> 1) * (MT / 2), wn = (wid & 1) << 6;
  const int fr = lane & 15, quad = lane >> 4;
  const int r0 = tid >> 2, c8 = (tid & 3) << 3;
  const int m0 = blockIdx.x * MT, n0 = blockIdx.y * 128;

  f32x4 acc[AFR][4] = {};

  const u16* BTe = (EPI == 6) ? BT + (size_t)blockIdx.z * 589824 : BT;
  const u16* gB0 = BTe + (size_t)(n0 + r0) * KDIM + c8;
  const u16* gA0 = A + (size_t)(m0 + r0) * KDIM + c8;

  short8 a00, a01, a10, a11, b00, b01, b10, b11;
  auto stage_load = [&](int kt) {
    a00 = *(const short8*)(gA0 + kt);
    a10 = *(const short8*)(gA0 + kt + 32);
    if (MT == 128) {
      a01 = *(const short8*)(gA0 + kt + (size_t)64 * KDIM);
      a11 = *(const short8*)(gA0 + kt + 32 + (size_t)64 * KDIM);
    }
    b00 = *(const short8*)(gB0 + kt);
    b01 = *(const short8*)(gB0 + kt + (size_t)64 * KDIM);
    b10 = *(const short8*)(gB0 + kt + 32);
    b11 = *(const short8*)(gB0 + kt + 32 + (size_t)64 * KDIM);
  };

  stage_load(0);

#pragma unroll 1
  for (int kt = 0; kt < KDIM; kt += 64) {
    __syncthreads();
    *(short8*)&smem[SWZ_W(tid)] = a00;
    if (MT == 128) *(short8*)&smem[2048 + SWZ_W(tid)] = a01;
    *(short8*)&smem[MT * 32 + SWZ_W(tid)] = a10;
    if (MT == 128) *(short8*)&smem[MT * 32 + 2048 + SWZ_W(tid)] = a11;
    *(short8*)&smem[MT * 64 + SWZ_W(tid)]        = b00;
    *(short8*)&smem[MT * 64 + 2048 + SWZ_W(tid)] = b01;
    *(short8*)&smem[MT * 64 + 4096 + SWZ_W(tid)] = b10;
    *(short8*)&smem[MT * 64 + 6144 + SWZ_W(tid)] = b11;
    __syncthreads();
    if (kt + 64 < KDIM) stage_load(kt + 64);
#pragma unroll
    for (int kh = 0; kh < 2; ++kh) {
      const int ao = kh * MT * 32, bo = MT * 64 + kh * 4096;
      short8 af[AFR], bfg[4];
#pragma unroll
      for (int i = 0; i < AFR; ++i)
        af[i] = *(const short8*)&smem[ao + SWZ_R(wm + i * 16 + fr, quad)];
#pragma unroll
      for (int i = 0; i < 4; ++i)
        bfg[i] = *(const short8*)&smem[bo + SWZ_R(wn + i * 16 + fr, quad)];
#pragma unroll
      for (int mt = 0; mt < AFR; ++mt)
#pragma unroll
        for (int nt = 0; nt < 4; ++nt)
          acc[mt][nt] = __builtin_amdgcn_mfma_f32_16x16x32_bf16(
              af[mt], bfg[nt], acc[mt][nt], 0, 0, 0);
    }
  }

  int isbf = 0;
  if (EPI == 5) isbf = probe_bf(fl);

#pragma unroll
  for (int mt = 0; mt < AFR; ++mt) {
#pragma unroll
    for (int nt = 0; nt < 4; ++nt) {
#pragma unroll
      for (int r = 0; r < 4; ++r) {
        int t = m0 + wm + mt * 16 + quad * 4 + r;
        int n = n0 + wn + nt * 16 + fr;
        float v = acc[mt][nt][r];
        if (EPI == 2) {  // delta bf16 ; BC raw f32
          if (n < DI) {
            float xx = v + bf2f(bias[n]);
            float sp = (xx > 20.f) ? xx : log1pf(__expf(xx));
            ob1[(size_t)t * DI + n] = f2bf(sp);
          } else if (n < DI + 32) {
            o2[(size_t)t * 32 + (n - DI)] = v;
          }
        } else if (EPI == 3) {
          o1[(size_t)t * DM + n] = v;
        } else if (EPI == 5) {
          float val = v + res[(size_t)t * DM + n];
          if (isbf) ob1[(size_t)t * DM + n] = f2bf(val);
          else      o1[(size_t)t * DM + n] = val;
        } else if (EPI == 6) {
          ob1[(size_t)n * 1536 + blockIdx.z * 384 + t] = f2bf(v);
        }
      }
    }
  }
}

// Merged z + conv GEMM, MT=64, BK=64, single-buffer swizzled LDS (r12).
// blockIdx.y < 6: xconv = silu(sum_tap h1[l-1+tap] @ Wcomb[tap] + b), K=1536
// blockIdx.y >= 6: zbuf = h1[l] @ Win_z, K=384 (rowoff 1).
__global__ __launch_bounds__(256) void gemm_xz(
    const u16* __restrict__ A, const u16* __restrict__ WC,
    const u16* __restrict__ WZ, u16* __restrict__ xconv,
    u16* __restrict__ zbuf, const u16* __restrict__ bias) {
  __shared__ u16 smem[12288];  // A0 @0, A1 @2048, B0 @4096, B1 @8192
  const int tid = threadIdx.x;
  const int lane = tid & 63, wid = tid >> 6;
  const int wm = (wid >> 1) << 5, wn = (wid & 1) << 6;
  const int fr = lane & 15, quad = lane >> 4;
  const int r0 = tid >> 2, c8 = (tid & 3) << 3;
  const int yb = blockIdx.y;
  const bool isz = yb >= 6;
  const int kd = isz ? 384 : 1536;
  const u16* BT = isz ? WZ : WC;
  const int kldb = isz ? 384 : 1536;
  const int n0 = (isz ? yb - 6 : yb) * 128;
  const int m0 = blockIdx.x * 64;

  f32x4 acc[2][4] = {};

  const u16* gB0 = BT + (size_t)(n0 + r0) * kldb + c8;
  const int b = m0 >> 11, l0 = m0 & 2047;
  const u16* gA0 = A + (size_t)(b * 2051 + l0 + r0 + (isz ? 1 : 0)) * DM + c8;

  short8 a0, a1, b00, b01, b10, b11;
  int wconv = 0, i0 = 0;
  auto calcA = [&]() -> const u16* {
    const u16* p = gA0 + (size_t)wconv * DM + i0;
    i0 += 32;
    if (i0 == DM) { i0 = 0; ++wconv; }
    return p;
  };
  auto stage_load = [&](int kt) {
    a0 = *(const short8*)calcA();
    a1 = *(const short8*)calcA();
    b00 = *(const short8*)(gB0 + kt);
    b01 = *(const short8*)(gB0 + kt + (size_t)64 * kldb);
    b10 = *(const short8*)(gB0 + kt + 32);
    b11 = *(const short8*)(gB0 + kt + 32 + (size_t)64 * kldb);
  };

  stage_load(0);

#pragma unroll 1
  for (int kt = 0; kt < kd; kt += 64) {
    __syncthreads();
    *(short8*)&smem[SWZ_W(tid)]         = a0;
    *(short8*)&smem[2048 + SWZ_W(tid)]  = a1;
    *(short8*)&smem[4096 + SWZ_W(tid)]  = b00;
    *(short8*)&smem[6144 + SWZ_W(tid)]  = b01;
    *(short8*)&smem[8192 + SWZ_W(tid)]  = b10;
    *(short8*)&smem[10240 + SWZ_W(tid)] = b11;
    __syncthreads();
    if (kt + 64 < kd) stage_load(kt + 64);
#pragma unroll
    for (int kh = 0; kh < 2; ++kh) {
      const int ao = kh * 2048, bo = 4096 + kh * 4096;
      short8 af[2], bfg[4];
#pragma unroll
      for (int i = 0; i < 2; ++i)
        af[i] = *(const short8*)&smem[ao + SWZ_R(wm + i * 16 + fr, quad)];
#pragma unroll
      for (int i = 0; i < 4; ++i)
        bfg[i] = *(const short8*)&smem[bo + SWZ_R(wn + i * 16 + fr, quad)];
#pragma unroll
      for (int mt = 0; mt < 2; ++mt)
#pragma unroll
        for (int nt = 0; nt < 4; ++nt)
          acc[mt][nt] = __builtin_amdgcn_mfma_f32_16x16x32_bf16(
              af[mt], bfg[nt], acc[mt][nt], 0, 0, 0);
    }
  }

#pragma unroll
  for (int mt = 0; mt < 2; ++mt) {
#pragma unroll
    for (int nt = 0; nt < 4; ++nt) {
#pragma unroll
      for (int r = 0; r < 4; ++r) {
        int t = m0 + wm + mt * 16 + quad * 4 + r;
        int n = n0 + wn + nt * 16 + fr;
        float v = acc[mt][nt][r];
        if (isz) {
          zbuf[(size_t)t * DI + n] = f2bf(v);
        } else {
          float xx = v + bf2f(bias[n]);
          float sg = 1.f / (1.f + __expf(-xx));
          xconv[(size_t)t * DI + n] = f2bf(xx * sg);
        }
      }
    }
  }
}

// Fused FFN gate|up GEMM + GLU, MT=64, BK=64, single-buffer swizzled (r12).
__global__ __launch_bounds__(256) void gemm_gu(
    const u16* __restrict__ A, const u16* __restrict__ W6T,
    u16* __restrict__ hid) {
  __shared__ u16 smem[20480];
  const int tid = threadIdx.x;
  const int lane = tid & 63, wid = tid >> 6;
  const int wm = (wid >> 1) << 5, wn = (wid & 1) << 6;
  const int fr = lane & 15, quad = lane >> 4;
  const int r0 = tid >> 2, c8 = (tid & 3) << 3;
  const int m0 = blockIdx.x * 64, n0 = blockIdx.y * 128;

  f32x4 accg[2][4] = {}, accu[2][4] = {};

  const u16* gA0 = A + (size_t)(m0 + r0) * DM + c8;
  const u16* gG0 = W6T + (size_t)(n0 + r0) * DM + c8;
  const u16* gU0 = W6T + (size_t)(1024 + n0 + r0) * DM + c8;

  short8 a0, a1, g00, g01, g10, g11, u00, u01, u10, u11;
  auto stage_load = [&](int kt) {
    a0  = *(const short8*)(gA0 + kt);
    a1  = *(const short8*)(gA0 + kt + 32);
    g00 = *(const short8*)(gG0 + kt);
    g01 = *(const short8*)(gG0 + kt + (size_t)64 * DM);
    g10 = *(const short8*)(gG0 + kt + 32);
    g11 = *(const short8*)(gG0 + kt + 32 + (size_t)64 * DM);
    u00 = *(const short8*)(gU0 + kt);
    u01 = *(const short8*)(gU0 + kt + (size_t)64 * DM);
    u10 = *(const short8*)(gU0 + kt + 32);
    u11 = *(const short8*)(gU0 + kt + 32 + (size_t)64 * DM);
  };

  stage_load(0);

#pragma unroll 1
  for (int kt = 0; kt < DM; kt += 64) {
    __syncthreads();
    *(short8*)&smem[SWZ_W(tid)]          = a0;
    *(short8*)&smem[2048 + SWZ_W(tid)]   = a1;
    *(short8*)&smem[4096 + SWZ_W(tid)]   = g00;
    *(short8*)&smem[6144 + SWZ_W(tid)]   = g01;
    *(short8*)&smem[8192 + SWZ_W(tid)]   = g10;
    *(short8*)&smem[10240 + SWZ_W(tid)]  = g11;
    *(short8*)&smem[12288 + SWZ_W(tid)]  = u00;
    *(short8*)&smem[14336 + SWZ_W(tid)]  = u01;
    *(short8*)&smem[16384 + SWZ_W(tid)]  = u10;
    *(short8*)&smem[18432 + SWZ_W(tid)]  = u11;
    __syncthreads();
    if (kt + 64 < DM) stage_load(kt + 64);
#pragma unroll
    for (int kh = 0; kh < 2; ++kh) {
      const int ao = kh * 2048, go = 4096 + kh * 4096, uo = 12288 + kh * 4096;
      short8 af[2], bg[4], bu[4];
#pragma unroll
      for (int i = 0; i < 2; ++i)
        af[i] = *(const short8*)&smem[ao + SWZ_R(wm + i * 16 + fr, quad)];
#pragma unroll
      for (int i = 0; i < 4; ++i) {
        bg[i] = *(const short8*)&smem[go + SWZ_R(wn + i * 16 + fr, quad)];
        bu[i] = *(const short8*)&smem[uo + SWZ_R(wn + i * 16 + fr, quad)];
      }
#pragma unroll
      for (int mt = 0; mt < 2; ++mt)
#pragma unroll
        for (int nt = 0; nt < 4; ++nt) {
          accg[mt][nt] = __builtin_amdgcn_mfma_f32_16x16x32_bf16(
              af[mt], bg[nt], accg[mt][nt], 0, 0, 0);
          accu[mt][nt] = __builtin_amdgcn_mfma_f32_16x16x32_bf16(
              af[mt], bu[nt], accu[mt][nt], 0, 0, 0);
        }
    }
  }

#pragma unroll
  for (int mt = 0; mt < 2; ++mt) {
#pragma unroll
    for (int nt = 0; nt < 4; ++nt) {
#pragma unroll
      for (int r = 0; r < 4; ++r) {
        int t = m0 + wm + mt * 16 + quad * 4 + r;
        int n = n0 + wn + nt * 16 + fr;
        float g = accg[mt][nt][r];
        float u = accu[mt][nt][r];
        float sg = 1.f / (1.f + __expf(-g));
        hid[(size_t)t * 1024 + n] = f2bf(g * sg * u);
      }
    }
  }
}

// ---------------------------------------------------------------- scan ----
// Fat threads: 16 states/thread, NCH=64 chunks of 32, next-row prefetch.
__global__ __launch_bounds__(256) void k_scan1(
    const u16* __restrict__ deltab, const u16* __restrict__ xconv,
    const float* __restrict__ BC, const float* __restrict__ An2T,
    float* __restrict__ hlb, float* __restrict__ Pb) {
  int gid = blockIdx.x * 256 + threadIdx.x;
  int d = gid % DI, bc = gid / DI, c = bc & (NCH - 1), b = bc >> 6;
  float An[NST];
#pragma unroll
  for (int n = 0; n < NST; ++n) An[n] = An2T[n * DI + d];
  float h[NST], P[NST];
#pragma unroll
  for (int n = 0; n < NST; ++n) { h[n] = 0.f; P[n] = 1.f; }
  int row0 = b * LSEQ + c * LCH;
  float dt = bf2f(deltab[(size_t)row0 * DI + d]);
  float xv = bf2f(xconv[(size_t)row0 * DI + d]);
  float4 q[4];
  {
    const float4* q4 = (const float4*)(BC + (size_t)row0 * 32);
#pragma unroll
    for (int i = 0; i < 4; ++i) q[i] = q4[i];
  }
  for (int s = 0; s < LCH; ++s) {
    float dtc = dt, xvc = xv;
    float Bm[NST];
#pragma unroll
    for (int i = 0; i < 4; ++i) {
      Bm[4*i] = q[i].x; Bm[4*i+1] = q[i].y;
      Bm[4*i+2] = q[i].z; Bm[4*i+3] = q[i].w;
    }
    if (s + 1 < LCH) {
      int r2 = row0 + s + 1;
      dt = bf2f(deltab[(size_t)r2 * DI + d]);
      xv = bf2f(xconv[(size_t)r2 * DI + d]);
      const float4* q4 = (const float4*)(BC + (size_t)r2 * 32);
#pragma unroll
      for (int i = 0; i < 4; ++i) q[i] = q4[i];
    }
    float dxv = dtc * xvc;
#pragma unroll
    for (int n = 0; n < NST; ++n) {
      float a = fexp2(dtc * An[n]);
      h[n] = fmaf(a, h[n], dxv * Bm[n]);
      P[n] *= a;
    }
  }
  float4* ph = (float4*)(hlb + (size_t)gid * NST);
  float4* pp = (float4*)(Pb + (size_t)gid * NST);
#pragma unroll
  for (int i = 0; i < 4; ++i) {
    ph[i] = make_float4(h[4*i], h[4*i+1], h[4*i+2], h[4*i+3]);
    pp[i] = make_float4(P[4*i], P[4*i+1], P[4*i+2], P[4*i+3]);
  }
}

__global__ __launch_bounds__(256) void k_scan2(const float* __restrict__ hlb,
                                               const float* __restrict__ Pb,
                                               float* __restrict__ hin) {
  int gid = blockIdx.x * 256 + threadIdx.x;  // (b*DI+d)*16+n
  int n = gid & 15, bd = gid >> 4;
  int d = bd % DI, b = bd / DI;
  float H = 0.f;
  for (int c = 0; c < NCH; ++c) {
    size_t idx = ((size_t)((b * NCH + c) * DI + d)) * NST + n;
    hin[idx] = H;
    H = hlb[idx] + Pb[idx] * H;
  }
}

__global__ __launch_bounds__(256) void k_scan3(
    const u16* __restrict__ deltab, const u16* __restrict__ xconv,
    const float* __restrict__ BC, const float* __restrict__ An2T,
    const float* __restrict__ hinb, const u16* __restrict__ zb,
    const u16* __restrict__ vecs, u16* __restrict__ ys) {
  int gid = blockIdx.x * 256 + threadIdx.x;
  int d = gid % DI, bc = gid / DI, c = bc & (NCH - 1), b = bc >> 6;
  float An[NST];
#pragma unroll
  for (int n = 0; n < NST; ++n) An[n] = An2T[n * DI + d];
  float h[NST];
  {
    const float4* hp = (const float4*)(hinb + (size_t)gid * NST);
#pragma unroll
    for (int i = 0; i < 4; ++i) {
      float4 t = hp[i];
      h[4*i] = t.x; h[4*i+1] = t.y; h[4*i+2] = t.z; h[4*i+3] = t.w;
    }
  }
  float Dd = bf2f(vecs[V_DP + d]);
  int row0 = b * LSEQ + c * LCH;
  float dt = bf2f(deltab[(size_t)row0 * DI + d]);
  float xv = bf2f(xconv[(size_t)row0 * DI + d]);
  float zv = bf2f(zb[(size_t)row0 * DI + d]);
  float4 q[8];
  {
    const float4* q4 = (const float4*)(BC + (size_t)row0 * 32);
#pragma unroll
    for (int i = 0; i < 8; ++i) q[i] = q4[i];
  }
  for (int s = 0; s < LCH; ++s) {
    int row = row0 + s;
    float dtc = dt, xvc = xv, zvc = zv;
    float Bm[NST], Cm[NST];
#pragma unroll
    for (int i = 0; i < 4; ++i) {
      Bm[4*i] = q[i].x;   Bm[4*i+1] = q[i].y;
      Bm[4*i+2] = q[i].z; Bm[4*i+3] = q[i].w;
      Cm[4*i] = q[4+i].x;   Cm[4*i+1] = q[4+i].y;
      Cm[4*i+2] = q[4+i].z; Cm[4*i+3] = q[4+i].w;
    }
    if (s + 1 < LCH) {
      int r2 = row + 1;
      dt = bf2f(deltab[(size_t)r2 * DI + d]);
      xv = bf2f(xconv[(size_t)r2 * DI + d]);
      zv = bf2f(zb[(size_t)r2 * DI + d]);
      const float4* q4 = (const float4*)(BC + (size_t)r2 * 32);
#pragma unroll
      for (int i = 0; i < 8; ++i) q[i] = q4[i];
    }
    float dxv = dtc * xvc;
    float yp[4] = {0.f, 0.f, 0.f, 0.f};
#pragma unroll
    for (int n = 0; n < NST; ++n) {
      float a = fexp2(dtc * An[n]);
      h[n] = fmaf(a, h[n], dxv * Bm[n]);
      yp[n & 3] = fmaf(h[n], Cm[n], yp[n & 3]);
    }
    float y = (yp[0] + yp[1]) + (yp[2] + yp[3]);
    float sz = zvc / (1.f + __expf(-zvc));
    ys[(size_t)row * DI + d] = f2bf((y + Dd * xvc) * sz);
  }
}

// ---------------------------------------------------------------- host ----
extern "C" void kernel_launch(void* const* d_in, const int* in_sizes, int n_in,
                              void* d_out, int out_size, void* d_ws,
                              size_t ws_size, hipStream_t stream) {
  (void)in_sizes; (void)n_in; (void)out_size;
  const void* x        = d_in[0];
  const void* rms1_w   = d_in[1];
  const void* rms2_w   = d_in[2];
  const void* in_proj  = d_in[3];
  const void* conv_w   = d_in[4];
  const void* conv_b   = d_in[5];
  const void* x_proj   = d_in[6];
  const void* dt_w     = d_in[7];
  const void* dt_b     = d_in[8];
  const void* A_log    = d_in[9];
  const void* Dp       = d_in[10];
  const void* out_proj = d_in[11];
  const void* gamma    = d_in[12];
  const void* beta     = d_in[13];
  const void* gate_w   = d_in[14];
  const void* up_w     = d_in[15];
  const void* down_w   = d_in[16];

  char* ws = (char*)d_ws;
  size_t off = 0;
  auto alloc = [&](size_t bytes) -> void* {
    void* p = ws + off;
    off = (off + bytes + 255) & ~(size_t)255;
    return p;
  };
  // weights (persistent), bf16 [N][K]
  u16*   W1T   = (u16*)alloc((size_t)1536 * 384 * 2);
  u16*   WCT   = (u16*)alloc((size_t)4 * 768 * 768 * 2);
  u16*   W45T  = (u16*)alloc((size_t)896 * 768 * 2);
  u16*   W5T   = (u16*)alloc((size_t)384 * 768 * 2);
  u16*   W6T   = (u16*)alloc((size_t)2048 * 384 * 2);
  u16*   W7T   = (u16*)alloc((size_t)384 * 1024 * 2);
  float* An2T  = (float*)alloc((size_t)16 * 768 * 4);
  u16*   vecs  = (u16*)alloc(3840 * 2);
  u16*   WinX  = (u16*)alloc((size_t)384 * 768 * 2);
  u16*   WcombT= (u16*)alloc((size_t)768 * 1536 * 2);
  // activations
  u16*   h1pad = (u16*)alloc((size_t)4 * 2051 * 384 * 2);  // prep -> gemm_xz
  u16*   zbuf  = (u16*)alloc((size_t)8192 * 768 * 2);      // gemm_xz -> scan3
  u16*   xconv = (u16*)alloc((size_t)8192 * 768 * 2);      // gemm_xz -> scan3
  u16*   deltab= (u16*)alloc((size_t)8192 * 768 * 2);      // gemm2 -> scan3
  float* BCb   = (float*)alloc((size_t)8192 * 32 * 4);     // gemm2 -> scan3
  float* hl    = (float*)alloc((size_t)196608 * 16 * 4);   // scan1 -> scan2
  float* Pb    = (float*)alloc((size_t)196608 * 16 * 4);   // scan1 -> scan2
  float* hin   = (float*)alloc((size_t)196608 * 16 * 4);   // scan2 -> scan3
  // ~96 MB total.  Aliases (write begins after host region's last read):
  u16*   ys   = (u16*)hl;     // scan3 -> gemm3  (hl dead after scan2)
  float* outm = Pb;           // gemm3 -> lnrms  (Pb dead after scan2)
  float* x2f  = hin;          // lnrms -> gemm5  (hin dead after scan3)
  u16*   h2   = h1pad;        // lnrms -> gemm_gu (h1pad dead after gemm_xz)
  u16*   hid  = (u16*)hl;     // gemm_gu -> gemm5 (ys dead after gemm3,
                              //   Pb=outm dead after lnrms; spans both)

  if (off > ws_size) return;  // ws-too-small signal: absmax == max|ref|

  // prep: tiled weight transposes + rms1 + WinX + An2T + vecs + halo
  k_prep<<<6565, 256, 0, stream>>>(
      x, in_proj, conv_w, dt_w, x_proj, out_proj, gate_w, up_w, down_w,
      A_log, conv_b, dt_b, Dp, rms1_w, rms2_w, gamma, beta,
      W1T, WCT, W45T, W5T, W6T, W7T, An2T, vecs, WinX, h1pad);

  // Wcomb[tap] = Win_x @ Wc[tap] -> WcombT [768][4*384]
  gemm_bt<6, 128, 768><<<dim3(3, 6, 4), 256, 0, stream>>>(
      WinX, WCT, nullptr, nullptr, WcombT, nullptr, nullptr, nullptr, nullptr);

  // merged MT=64: y<6 -> xconv (K=1536, silu) ; y>=6 -> zbuf (K=384)
  gemm_xz<<<dim3(128, 12), 256, 0, stream>>>(
      h1pad, WcombT, W1T + (size_t)768 * 384, xconv, zbuf, vecs + V_CB);

  // delta = softplus(x_conv@dt_w + b) (bf16) ; BC = x_conv@x_proj (f32)
  gemm_bt<2, 64, 768><<<dim3(128, 7), 256, 0, stream>>>(
      xconv, W45T, nullptr, BCb, deltab, nullptr, vecs + V_DB, nullptr,
      nullptr);

  k_scan1<<<768, 256, 0, stream>>>(deltab, xconv, BCb, An2T, hl, Pb);
  k_scan2<<<192, 256, 0, stream>>>(hl, Pb, hin);
  k_scan3<<<768, 256, 0, stream>>>(deltab, xconv, BCb, An2T, hin, zbuf, vecs,
                                   ys);

  // out = ys @ out_proj (f32)
  gemm_bt<3, 64, 768><<<dim3(128, 3), 256, 0, stream>>>(
      ys, W5T, outm, nullptr, nullptr, nullptr, nullptr, nullptr, nullptr);
  k_lnrms<<<8192, 128, 0, stream>>>(outm, x, rms1_w, vecs, x2f, h2);

  // fused gate|up GEMM + GLU -> hid ; down + residual -> out
  gemm_gu<<<dim3(128, 8), 256, 0, stream>>>(h2, W6T, hid);
  gemm_bt<5, 64, 1024><<<dim3(128, 3), 256, 0, stream>>>(
      hid, W7T, (float*)d_out, nullptr, (u16*)d_out, nullptr, nullptr, x2f,
      rms1_w);
}

// Round 16
// 332.429 us; speedup vs baseline: 1.0978x; 1.0077x over previous
//
#include <hip/hip_runtime.h>
#include <hip/hip_bf16.h>

// ImprovedCobrablock on MI355X (gfx950).
// Inputs/output f32 (verified r3). bf16 MFMA GEMMs, f32 scan state.
// GEMM: register staging + prefetch (r5), BK=64 (r11), XOR swizzle (r12).
// Conv folded into Wcomb (r7). Fat-thread scan NCH=64 (r8). MT=64 + z/conv
// merge (r9). gemm_gu fusion (r10). Tiled-transpose prep + rms1 fold (r15).
// r16: NT=64 tiles for gemm_xz (grid 1536->3072, LDS 24->16KB) and EPI=2
// (grid 896->1664) — every prior grid-doubling won; xz still at occ 32%,
// MfmaUtil 19%. EPI 3/5/6 + gu stay NT=128 (template, r15-identical).
// B=4, L=2048, D=384, Di=768, N=16, K=4, FFN=1024, T=8192.

using u16 = unsigned short;
using u32 = unsigned int;
using short8 = __attribute__((ext_vector_type(8))) short;
using f32x4  = __attribute__((ext_vector_type(4))) float;

#define TTOK 8192
#define DM 384
#define DI 768
#define NST 16
#define LSEQ 2048
#define NCH 64   /* chunks per sequence */
#define LCH 32   /* chunk length */

// LDS tile layout: [rows][32 u16], 4 chunks of 8 u16 per row, XOR-swizzled.
#define SWZ_R(row, quad) \
  ((row) * 32 + ((((quad) ^ (row) ^ ((row) >> 2)) & 3) * 8))
#define SWZ_W(tid) SWZ_R((tid) >> 2, (tid) & 3)

__device__ __forceinline__ float bf2f(u16 a) {
  u32 u = ((u32)a) << 16;
  float f; __builtin_memcpy(&f, &u, 4); return f;
}
__device__ __forceinline__ u16 f2bf(float f) {
  u32 u; __builtin_memcpy(&u, &f, 4);
  u32 r = (u + 0x7fffu + ((u >> 16) & 1u)) >> 16;  // RNE
  return (u16)r;
}
__device__ __forceinline__ int probe_bf(const void* rw) {
  return (((const u32*)rw)[0] == 0x3F803F80u) ? 1 : 0;
}
__device__ __forceinline__ float ld_in(const void* p, int i, int isbf) {
  return isbf ? bf2f(((const u16*)p)[i]) : ((const float*)p)[i];
}
__device__ __forceinline__ float fexp2(float x) {
#if __has_builtin(__builtin_amdgcn_exp2f)
  return __builtin_amdgcn_exp2f(x);
#else
  return exp2f(x);
#endif
}
__device__ __forceinline__ float wave_sum(float v) {
#pragma unroll
  for (int off = 32; off > 0; off >>= 1) v += __shfl_xor(v, off, 64);
  return v;
}

// vecs[] layout offsets
#define V_CB 0
#define V_DB 768
#define V_DP 1536
#define V_R1 2304
#define V_R2 2688
#define V_GA 3072
#define V_BE 3456

// ---------------------------------------------------------------- prep ----
// One dispatch, block ranges:
// [0,1236): 64x64 LDS-tiled transposes (coalesced loads AND stores)
// [1236,5332): rms1 (2 tokens/block) -> h1pad interior rows
// [5332,6484): WinX copy (294912 elems = 1152 blocks exactly)
// [6484,6532): A_log->An2T   [6532,6547): vecs   [6547,6565): halo zero
__global__ __launch_bounds__(256) void k_prep(
    const void* __restrict__ x, const void* __restrict__ in_proj,
    const void* __restrict__ conv_w, const void* __restrict__ dt_w,
    const void* __restrict__ x_proj, const void* __restrict__ out_proj,
    const void* __restrict__ gate_w, const void* __restrict__ up_w,
    const void* __restrict__ down_w, const void* __restrict__ A_log,
    const void* __restrict__ conv_b, const void* __restrict__ dt_b,
    const void* __restrict__ Dp, const void* __restrict__ rms1_w,
    const void* __restrict__ rms2_w, const void* __restrict__ gamma,
    const void* __restrict__ beta,
    u16* __restrict__ W1T, u16* __restrict__ WCT, u16* __restrict__ W45T,
    u16* __restrict__ W5T, u16* __restrict__ W6T, u16* __restrict__ W7T,
    float* __restrict__ An2T, u16* __restrict__ vecs,
    u16* __restrict__ WinX, u16* __restrict__ h1pad) {
  const int isbf = probe_bf(rms1_w);
  const int bx = blockIdx.x;
  const int tid = threadIdx.x;
  __shared__ u16 lt[64 * 66];  // stride 66 u16 = 33 dwords -> <=2-way banks

  if (bx < 1236) {  // tiled transpose: dst[c][r] = src[r][c]
    const void* src; size_t soff = 0; u16* dst; int R, C, tpr, lo;
    if (bx < 144)       { src = in_proj;  dst = W1T;  R = 384;  C = 1536; tpr = 24; lo = bx; }
    else if (bx < 720)  { int tp = (bx - 144) / 144; lo = (bx - 144) % 144;
                          src = conv_w; soff = (size_t)tp * 589824;
                          dst = WCT + (size_t)tp * 589824; R = 768; C = 768; tpr = 12; }
    else if (bx < 864)  { src = dt_w;     dst = W45T; R = 768;  C = 768;  tpr = 12; lo = bx - 720; }
    else if (bx < 876)  { src = x_proj;   dst = W45T + (size_t)768 * 768;
                          R = 768; C = 32; tpr = 1; lo = bx - 864; }
    else if (bx < 948)  { src = out_proj; dst = W5T;  R = 768;  C = 384;  tpr = 6;  lo = bx - 876; }
    else if (bx < 1044) { src = gate_w;   dst = W6T;  R = 384;  C = 1024; tpr = 16; lo = bx - 948; }
    else if (bx < 1140) { src = up_w;     dst = W6T + (size_t)1024 * 384;
                          R = 384; C = 1024; tpr = 16; lo = bx - 1044; }
    else                { src = down_w;   dst = W7T;  R = 1024; C = 384;  tpr = 6;  lo = bx - 1140; }
    int tr = lo / tpr, tc = lo % tpr;
    int r0 = tr * 64, c0 = tc * 64;
#pragma unroll
    for (int i = 0; i < 16; ++i) {
      int el = i * 256 + tid, lr = el >> 6, lc = el & 63;
      if (c0 + lc < C)
        lt[lr * 66 + lc] =
            f2bf(ld_in(src, (int)(soff + (size_t)(r0 + lr) * C + c0 + lc), isbf));
    }
    __syncthreads();
#pragma unroll
    for (int i = 0; i < 16; ++i) {
      int el = i * 256 + tid, orow = el >> 6, oc = el & 63;
      if (c0 + orow < C)
        dst[(size_t)(c0 + orow) * R + r0 + oc] = lt[oc * 66 + orow];
    }
    return;
  }
  if (bx < 5332) {  // rms1: 2 tokens per block (waves 0-1 / 2-3)
    int half = tid >> 7;
    int t = (bx - 1236) * 2 + half;
    int tid2 = tid & 127;
    int lane = tid & 63, wv = tid >> 6;
    float v[3]; float q = 0.f;
#pragma unroll
    for (int j = 0; j < 3; ++j) {
      v[j] = ld_in(x, t * DM + tid2 + j * 128, isbf);
      q += v[j] * v[j];
    }
    q = wave_sum(q);
    float* rq = (float*)lt;
    if (lane == 0) rq[wv] = q;
    __syncthreads();
    float rr = rsqrtf((rq[half * 2] + rq[half * 2 + 1]) * (1.f / DM) + 1e-6f);
    int b = t >> 11, l = t & 2047;
    size_t orow = ((size_t)(b * 2051 + l + 1)) * DM;
#pragma unroll
    for (int j = 0; j < 3; ++j) {
      int i = tid2 + j * 128;
      h1pad[orow + i] = f2bf(v[j] * rr * ld_in(rms1_w, i, isbf));
    }
    return;
  }
  if (bx < 6484) {  // WinX = in_proj[:, 0:768] as [384][768] bf16
    int lo = (bx - 5332) * 256 + tid;  // < 294912 exactly
    int i = lo / 768, j = lo % 768;
    WinX[lo] = f2bf(ld_in(in_proj, i * 1536 + j, isbf));
    return;
  }
  if (bx < 6532) {  // A_log [768][16] -> An2T [16][768] = -exp * log2e
    int lo = (bx - 6484) * 256 + tid;
    if (lo < 12288) {
      int d = lo >> 4, n = lo & 15;
      An2T[n * DI + d] = -__expf(ld_in(A_log, lo, isbf)) * 1.44269504f;
    }
    return;
  }
  if (bx < 6547) {  // small vectors -> bf16 vecs[]
    int lo = (bx - 6532) * 256 + tid;
    if (lo < 3840) {
      const void* s; int o;
      if      (lo < 768)  { s = conv_b; o = lo; }
      else if (lo < 1536) { s = dt_b;   o = lo - 768; }
      else if (lo < 2304) { s = Dp;     o = lo - 1536; }
      else if (lo < 2688) { s = rms1_w; o = lo - 2304; }
      else if (lo < 3072) { s = rms2_w; o = lo - 2688; }
      else if (lo < 3456) { s = gamma;  o = lo - 3072; }
      else                { s = beta;   o = lo - 3456; }
      vecs[lo] = f2bf(ld_in(s, o, isbf));
    }
    return;
  }
  {  // h1pad halo rows 0, 2049, 2050 per batch -> 0
    int lo = (bx - 6547) * 256 + tid;
    if (lo < 4608) {
      int b = lo / (3 * DM), rem = lo % (3 * DM);
      int which = rem / DM, i = rem % DM;
      int row = b * 2051 + (which == 0 ? 0 : (2048 + which));
      h1pad[(size_t)row * DM + i] = 0;
    }
  }
}

// ---------------------------------------------------------------- norms ---
__global__ __launch_bounds__(128) void k_lnrms(const float* __restrict__ outm,
                                               const void* __restrict__ xin,
                                               const void* __restrict__ rw,
                                               const u16* __restrict__ vecs,
                                               float* __restrict__ x2f,
                                               u16* __restrict__ h2) {
  const int isbf = probe_bf(rw);
  int t = blockIdx.x, tid = threadIdx.x;
  int lane = tid & 63, wid = tid >> 6;
  float v[3]; float s = 0.f, q = 0.f;
#pragma unroll
  for (int j = 0; j < 3; ++j) {
    v[j] = outm[(size_t)t * DM + tid + j * 128];
    s += v[j]; q += v[j] * v[j];
  }
  s = wave_sum(s); q = wave_sum(q);
  __shared__ float rs[2], rq[2], r2[2];
  if (lane == 0) { rs[wid] = s; rq[wid] = q; }
  __syncthreads();
  float mu = (rs[0] + rs[1]) * (1.f / DM);
  float var = (rq[0] + rq[1]) * (1.f / DM) - mu * mu;
  float rstd = rsqrtf(var + 1e-5f);
  float x2v[3]; float q2 = 0.f;
#pragma unroll
  for (int j = 0; j < 3; ++j) {
    int i = tid + j * 128;
    float ln = (v[j] - mu) * rstd * bf2f(vecs[V_GA + i]) + bf2f(vecs[V_BE + i]);
    x2v[j] = ld_in(xin, t * DM + i, isbf) + ln;
    x2f[(size_t)t * DM + i] = x2v[j];
    q2 += x2v[j] * x2v[j];
  }
  q2 = wave_sum(q2);
  if (lane == 0) r2[wid] = q2;
  __syncthreads();
  float rr = rsqrtf((r2[0] + r2[1]) * (1.f / DM) + 1e-6f);
#pragma unroll
  for (int j = 0; j < 3; ++j) {
    int i = tid + j * 128;
    h2[(size_t)t * DM + i] = f2bf(x2v[j] * rr * bf2f(vecs[V_R2 + i]));
  }
}

// ---------------------------------------------------------------- GEMM ----
// C[M,N] = A[M,K] @ BT[N,K]^T, MTxNT tile, BK=64, mfma 16x16x32 bf16,
// register staging + next-stage prefetch, XOR-swizzled single-buffer LDS.
// EPI: 2 softplus->delta(bf16)+BC(f32), 3 f32 raw ld DM,
//      5 +res -> d_out (dtype by flag), 6 Wcomb transposed write.
template <int EPI, int MT, int NT, int KDIM>
__global__ __launch_bounds__(256) void gemm_bt(
    const u16* __restrict__ A, const u16* __restrict__ BT,
    float* __restrict__ o1, float* __restrict__ o2,
    u16* __restrict__ ob1, u16* __restrict__ ob2,
    const u16* __restrict__ bias, const float* __restrict__ res,
    const void* __restrict__ fl) {
  constexpr int AFR = MT / 32, BFR = NT / 32;
  __shared__ u16 smem[MT * 64 + NT * 64];
  const int tid = threadIdx.x;
  const int lane = tid & 63, wid = tid >> 6;
  const int wm = (wid >> 1) * (MT / 2), wn = (wid & 1) * (NT / 2);
  const int fr = lane & 15, quad = lane >> 4;
  const int r0 = tid >> 2, c8 = (tid & 3) << 3;
  const int m0 = blockIdx.x * MT, n0 = blockIdx.y * NT;

  f32x4 acc[AFR][BFR] = {};

  const u16* BTe = (EPI == 6) ? BT + (size_t)blockIdx.z * 589824 : BT;
  const u16* gB0 = BTe + (size_t)(n0 + r0) * KDIM + c8;
  const u16* gA0 = A + (size_t)(m0 + r0) * KDIM + c8;

  short8 a00, a01, a10, a11, b00, b01, b10, b11;
  auto stage_load = [&](int kt) {
    a00 = *(const short8*)(gA0 + kt);
    a10 = *(const short8*)(gA0 + kt + 32);
    if (MT == 128) {
      a01 = *(const short8*)(gA0 + kt + (size_t)64 * KDIM);
      a11 = *(const short8*)(gA0 + kt + 32 + (size_t)64 * KDIM);
    }
    b00 = *(const short8*)(gB0 + kt);
    b10 = *(const short8*)(gB0 + kt + 32);
    if (NT == 128) {
      b01 = *(const short8*)(gB0 + kt + (size_t)64 * KDIM);
      b11 = *(const short8*)(gB0 + kt + 32 + (size_t)64 * KDIM);
    }
  };

  stage_load(0);

#pragma unroll 1
  for (int kt = 0; kt < KDIM; kt += 64) {
    __syncthreads();
    *(short8*)&smem[SWZ_W(tid)] = a00;
    if (MT == 128) *(short8*)&smem[2048 + SWZ_W(tid)] = a01;
    *(short8*)&smem[MT * 32 + SWZ_W(tid)] = a10;
    if (MT == 128) *(short8*)&smem[MT * 32 + 2048 + SWZ_W(tid)] = a11;
    *(short8*)&smem[MT * 64 + SWZ_W(tid)] = b00;
    if (NT == 128) *(short8*)&smem[MT * 64 + 2048 + SWZ_W(tid)] = b01;
    *(short8*)&smem[MT * 64 + NT * 32 + SWZ_W(tid)] = b10;
    if (NT == 128) *(short8*)&smem[MT * 64 + NT * 32 + 2048 + SWZ_W(tid)] = b11;
    __syncthreads();
    if (kt + 64 < KDIM) stage_load(kt + 64);
#pragma unroll
    for (int kh = 0; kh < 2; ++kh) {
      const int ao = kh * MT * 32, bo = MT * 64 + kh * NT * 32;
      short8 af[AFR], bfg[BFR];
#pragma unroll
      for (int i = 0; i < AFR; ++i)
        af[i] = *(const short8*)&smem[ao + SWZ_R(wm + i * 16 + fr, quad)];
#pragma unroll
      for (int i = 0; i < BFR; ++i)
        bfg[i] = *(const short8*)&smem[bo + SWZ_R(wn + i * 16 + fr, quad)];
#pragma unroll
      for (int mt = 0; mt < AFR; ++mt)
#pragma unroll
        for (int nt = 0; nt < BFR; ++nt)
          acc[mt][nt] = __builtin_amdgcn_mfma_f32_16x16x32_bf16(
              af[mt], bfg[nt], acc[mt][nt], 0, 0, 0);
    }
  }

  int isbf = 0;
  if (EPI == 5) isbf = probe_bf(fl);

#pragma unroll
  for (int mt = 0; mt < AFR; ++mt) {
#pragma unroll
    for (int nt = 0; nt < BFR; ++nt) {
#pragma unroll
      for (int r = 0; r < 4; ++r) {
        int t = m0 + wm + mt * 16 + quad * 4 + r;
        int n = n0 + wn + nt * 16 + fr;
        float v = acc[mt][nt][r];
        if (EPI == 2) {  // delta bf16 ; BC raw f32
          if (n < DI) {
            float xx = v + bf2f(bias[n]);
            float sp = (xx > 20.f) ? xx : log1pf(__expf(xx));
            ob1[(size_t)t * DI + n] = f2bf(sp);
          } else if (n < DI + 32) {
            o2[(size_t)t * 32 + (n - DI)] = v;
          }
        } else if (EPI == 3) {
          o1[(size_t)t * DM + n] = v;
        } else if (EPI == 5) {
          float val = v + res[(size_t)t * DM + n];
          if (isbf) ob1[(size_t)t * DM + n] = f2bf(val);
          else      o1[(size_t)t * DM + n] = val;
        } else if (EPI == 6) {
          ob1[(size_t)n * 1536 + blockIdx.z * 384 + t] = f2bf(v);
        }
      }
    }
  }
}

// Merged z + conv GEMM, MT=64, NT=64, BK=64, single-buffer swizzled LDS.
// blockIdx.y < 12: xconv tile n0=yb*64, K=1536 (Wcomb, silu epilogue)
// blockIdx.y >= 12: zbuf tile n0=(yb-12)*64, K=384 (Win_z, rowoff 1).
__global__ __launch_bounds__(256) void gemm_xz(
    const u16* __restrict__ A, const u16* __restrict__ WC,
    const u16* __restrict__ WZ, u16* __restrict__ xconv,
    u16* __restrict__ zbuf, const u16* __restrict__ bias) {
  __shared__ u16 smem[8192];  // A0 @0, A1 @2048, B0 @4096, B1 @6144
  const int tid = threadIdx.x;
  const int lane = tid & 63, wid = tid >> 6;
  const int wm = (wid >> 1) << 5, wn = (wid & 1) << 5;
  const int fr = lane & 15, quad = lane >> 4;
  const int r0 = tid >> 2, c8 = (tid & 3) << 3;
  const int yb = blockIdx.y;
  const bool isz = yb >= 12;
  const int kd = isz ? 384 : 1536;
  const u16* BT = isz ? WZ : WC;
  const int kldb = isz ? 384 : 1536;
  const int n0 = (isz ? yb - 12 : yb) * 64;
  const int m0 = blockIdx.x * 64;

  f32x4 acc[2][2] = {};

  const u16* gB0 = BT + (size_t)(n0 + r0) * kldb + c8;
  const int b = m0 >> 11, l0 = m0 & 2047;
  const u16* gA0 = A + (size_t)(b * 2051 + l0 + r0 + (isz ? 1 : 0)) * DM + c8;

  short8 a0, a1, b0, b1;
  int wconv = 0, i0 = 0;
  auto calcA = [&]() -> const u16* {
    const u16* p = gA0 + (size_t)wconv * DM + i0;
    i0 += 32;
    if (i0 == DM) { i0 = 0; ++wconv; }
    return p;
  };
  auto stage_load = [&](int kt) {
    a0 = *(const short8*)calcA();
    a1 = *(const short8*)calcA();
    b0 = *(const short8*)(gB0 + kt);
    b1 = *(const short8*)(gB0 + kt + 32);
  };

  stage_load(0);

#pragma unroll 1
  for (int kt = 0; kt < kd; kt += 64) {
    __syncthreads();
    *(short8*)&smem[SWZ_W(tid)]        = a0;
    *(short8*)&smem[2048 + SWZ_W(tid)] = a1;
    *(short8*)&smem[4096 + SWZ_W(tid)] = b0;
    *(short8*)&smem[6144 + SWZ_W(tid)] = b1;
    __syncthreads();
    if (kt + 64 < kd) stage_load(kt + 64);
#pragma unroll
    for (int kh = 0; kh < 2; ++kh) {
      const int ao = kh * 2048, bo = 4096 + kh * 2048;
      short8 af[2], bfg[2];
#pragma unroll
      for (int i = 0; i < 2; ++i)
        af[i] = *(const short8*)&smem[ao + SWZ_R(wm + i * 16 + fr, quad)];
#pragma unroll
      for (int i = 0; i < 2; ++i)
        bfg[i] = *(const short8*)&smem[bo + SWZ_R(wn + i * 16 + fr, quad)];
#pragma unroll
      for (int mt = 0; mt < 2; ++mt)
#pragma unroll
        for (int nt = 0; nt < 2; ++nt)
          acc[mt][nt] = __builtin_amdgcn_mfma_f32_16x16x32_bf16(
              af[mt], bfg[nt], acc[mt][nt], 0, 0, 0);
    }
  }

#pragma unroll
  for (int mt = 0; mt < 2; ++mt) {
#pragma unroll
    for (int nt = 0; nt < 2; ++nt) {
#pragma unroll
      for (int r = 0; r < 4; ++r) {
        int t = m0 + wm + mt * 16 + quad * 4 + r;
        int n = n0 + wn + nt * 16 + fr;
        float v = acc[mt][nt][r];
        if (isz) {
          zbuf[(size_t)t * DI + n] = f2bf(v);
        } else {
          float xx = v + bf2f(bias[n]);
          float sg = 1.f / (1.f + __expf(-xx));
          xconv[(size_t)t * DI + n] = f2bf(xx * sg);
        }
      }
    }
  }
}

// Fused FFN gate|up GEMM + GLU, MT=64, BK=64, single-buffer swizzled (r12).
__global__ __launch_bounds__(256) void gemm_gu(
    const u16* __restrict__ A, const u16* __restrict__ W6T,
    u16* __restrict__ hid) {
  __shared__ u16 smem[20480];
  const int tid = threadIdx.x;
  const int lane = tid & 63, wid = tid >> 6;
  const int wm = (wid >> 1) << 5, wn = (wid & 1) << 6;
  const int fr = lane & 15, quad = lane >> 4;
  const int r0 = tid >> 2, c8 = (tid & 3) << 3;
  const int m0 = blockIdx.x * 64, n0 = blockIdx.y * 128;

  f32x4 accg[2][4] = {}, accu[2][4] = {};

  const u16* gA0 = A + (size_t)(m0 + r0) * DM + c8;
  const u16* gG0 = W6T + (size_t)(n0 + r0) * DM + c8;
  const u16* gU0 = W6T + (size_t)(1024 + n0 + r0) * DM + c8;

  short8 a0, a1, g00, g01, g10, g11, u00, u01, u10, u11;
  auto stage_load = [&](int kt) {
    a0  = *(const short8*)(gA0 + kt);
    a1  = *(const short8*)(gA0 + kt + 32);
    g00 = *(const short8*)(gG0 + kt);
    g01 = *(const short8*)(gG0 + kt + (size_t)64 * DM);
    g10 = *(const short8*)(gG0 + kt + 32);
    g11 = *(const short8*)(gG0 + kt + 32 + (size_t)64 * DM);
    u00 = *(const short8*)(gU0 + kt);
    u01 = *(const short8*)(gU0 + kt + (size_t)64 * DM);
    u10 = *(const short8*)(gU0 + kt + 32);
    u11 = *(const short8*)(gU0 + kt + 32 + (size_t)64 * DM);
  };

  stage_load(0);

#pragma unroll 1
  for (int kt = 0; kt < DM; kt += 64) {
    __syncthreads();
    *(short8*)&smem[SWZ_W(tid)]          = a0;
    *(short8*)&smem[2048 + SWZ_W(tid)]   = a1;
    *(short8*)&smem[4096 + SWZ_W(tid)]   = g00;
    *(short8*)&smem[6144 + SWZ_W(tid)]   = g01;
    *(short8*)&smem[8192 + SWZ_W(tid)]   = g10;
    *(short8*)&smem[10240 + SWZ_W(tid)]  = g11;
    *(short8*)&smem[12288 + SWZ_W(tid)]  = u00;
    *(short8*)&smem[14336 + SWZ_W(tid)]  = u01;
    *(short8*)&smem[16384 + SWZ_W(tid)]  = u10;
    *(short8*)&smem[18432 + SWZ_W(tid)]  = u11;
    __syncthreads();
    if (kt + 64 < DM) stage_load(kt + 64);
#pragma unroll
    for (int kh = 0; kh < 2; ++kh) {
      const int ao = kh * 2048, go = 4096 + kh * 4096, uo = 12288 + kh * 4096;
      short8 af[2], bg[4], bu[4];
#pragma unroll
      for (int i = 0; i < 2; ++i)
        af[i] = *(const short8*)&smem[ao + SWZ_R(wm + i * 16 + fr, quad)];
#pragma unroll
      for (int i = 0; i < 4; ++i) {
        bg[i] = *(const short8*)&smem[go + SWZ_R(wn + i * 16 + fr, quad)];
        bu[i] = *(const short8*)&smem[uo + SWZ_R(wn + i * 16 + fr, quad)];
      }
#pragma unroll
      for (int mt = 0; mt < 2; ++mt)
#pragma unroll
        for (int nt = 0; nt < 4; ++nt) {
          accg[mt][nt] = __builtin_amdgcn_mfma_f32_16x16x32_bf16(
              af[mt], bg[nt], accg[mt][nt], 0, 0, 0);
          accu[mt][nt] = __builtin_amdgcn_mfma_f32_16x16x32_bf16(
              af[mt], bu[nt], accu[mt][nt], 0, 0, 0);
        }
    }
  }

#pragma unroll
  for (int mt = 0; mt < 2; ++mt) {
#pragma unroll
    for (int nt = 0; nt < 4; ++nt) {
#pragma unroll
      for (int r = 0; r < 4; ++r) {
        int t = m0 + wm + mt * 16 + quad * 4 + r;
        int n = n0 + wn + nt * 16 + fr;
        float g = accg[mt][nt][r];
        float u = accu[mt][nt][r];
        float sg = 1.f / (1.f + __expf(-g));
        hid[(size_t)t * 1024 + n] = f2bf(g * sg * u);
      }
    }
  }
}

// ---------------------------------------------------------------- scan ----
// Fat threads: 16 states/thread, NCH=64 chunks of 32, next-row prefetch.
__global__ __launch_bounds__(256) void k_scan1(
    const u16* __restrict__ deltab, const u16* __restrict__ xconv,
    const float* __restrict__ BC, const float* __restrict__ An2T,
    float* __restrict__ hlb, float* __restrict__ Pb) {
  int gid = blockIdx.x * 256 + threadIdx.x;
  int d = gid % DI, bc = gid / DI, c = bc & (NCH - 1), b = bc >> 6;
  float An[NST];
#pragma unroll
  for (int n = 0; n < NST; ++n) An[n] = An2T[n * DI + d];
  float h[NST], P[NST];
#pragma unroll
  for (int n = 0; n < NST; ++n) { h[n] = 0.f; P[n] = 1.f; }
  int row0 = b * LSEQ + c * LCH;
  float dt = bf2f(deltab[(size_t)row0 * DI + d]);
  float xv = bf2f(xconv[(size_t)row0 * DI + d]);
  float4 q[4];
  {
    const float4* q4 = (const float4*)(BC + (size_t)row0 * 32);
#pragma unroll
    for (int i = 0; i < 4; ++i) q[i] = q4[i];
  }
  for (int s = 0; s < LCH; ++s) {
    float dtc = dt, xvc = xv;
    float Bm[NST];
#pragma unroll
    for (int i = 0; i < 4; ++i) {
      Bm[4*i] = q[i].x; Bm[4*i+1] = q[i].y;
      Bm[4*i+2] = q[i].z; Bm[4*i+3] = q[i].w;
    }
    if (s + 1 < LCH) {
      int r2 = row0 + s + 1;
      dt = bf2f(deltab[(size_t)r2 * DI + d]);
      xv = bf2f(xconv[(size_t)r2 * DI + d]);
      const float4* q4 = (const float4*)(BC + (size_t)r2 * 32);
#pragma unroll
      for (int i = 0; i < 4; ++i) q[i] = q4[i];
    }
    float dxv = dtc * xvc;
#pragma unroll
    for (int n = 0; n < NST; ++n) {
      float a = fexp2(dtc * An[n]);
      h[n] = fmaf(a, h[n], dxv * Bm[n]);
      P[n] *= a;
    }
  }
  float4* ph = (float4*)(hlb + (size_t)gid * NST);
  float4* pp = (float4*)(Pb + (size_t)gid * NST);
#pragma unroll
  for (int i = 0; i < 4; ++i) {
    ph[i] = make_float4(h[4*i], h[4*i+1], h[4*i+2], h[4*i+3]);
    pp[i] = make_float4(P[4*i], P[4*i+1], P[4*i+2], P[4*i+3]);
  }
}

__global__ __launch_bounds__(256) void k_scan2(const float* __restrict__ hlb,
                                               const float* __restrict__ Pb,
                                               float* __restrict__ hin) {
  int gid = blockIdx.x * 256 + threadIdx.x;  // (b*DI+d)*16+n
  int n = gid & 15, bd = gid >> 4;
  int d = bd % DI, b = bd / DI;
  float H = 0.f;
  for (int c = 0; c < NCH; ++c) {
    size_t idx = ((size_t)((b * NCH + c) * DI + d)) * NST + n;
    hin[idx] = H;
    H = hlb[idx] + Pb[idx] * H;
  }
}

__global__ __launch_bounds__(256) void k_scan3(
    const u16* __restrict__ deltab, const u16* __restrict__ xconv,
    const float* __restrict__ BC, const float* __restrict__ An2T,
    const float* __restrict__ hinb, const u16* __restrict__ zb,
    const u16* __restrict__ vecs, u16* __restrict__ ys) {
  int gid = blockIdx.x * 256 + threadIdx.x;
  int d = gid % DI, bc = gid / DI, c = bc & (NCH - 1), b = bc >> 6;
  float An[NST];
#pragma unroll
  for (int n = 0; n < NST; ++n) An[n] = An2T[n * DI + d];
  float h[NST];
  {
    const float4* hp = (const float4*)(hinb + (size_t)gid * NST);
#pragma unroll
    for (int i = 0; i < 4; ++i) {
      float4 t = hp[i];
      h[4*i] = t.x; h[4*i+1] = t.y; h[4*i+2] = t.z; h[4*i+3] = t.w;
    }
  }
  float Dd = bf2f(vecs[V_DP + d]);
  int row0 = b * LSEQ + c * LCH;
  float dt = bf2f(deltab[(size_t)row0 * DI + d]);
  float xv = bf2f(xconv[(size_t)row0 * DI + d]);
  float zv = bf2f(zb[(size_t)row0 * DI + d]);
  float4 q[8];
  {
    const float4* q4 = (const float4*)(BC + (size_t)row0 * 32);
#pragma unroll
    for (int i = 0; i < 8; ++i) q[i] = q4[i];
  }
  for (int s = 0; s < LCH; ++s) {
    int row = row0 + s;
    float dtc = dt, xvc = xv, zvc = zv;
    float Bm[NST], Cm[NST];
#pragma unroll
    for (int i = 0; i < 4; ++i) {
      Bm[4*i] = q[i].x;   Bm[4*i+1] = q[i].y;
      Bm[4*i+2] = q[i].z; Bm[4*i+3] = q[i].w;
      Cm[4*i] = q[4+i].x;   Cm[4*i+1] = q[4+i].y;
      Cm[4*i+2] = q[4+i].z; Cm[4*i+3] = q[4+i].w;
    }
    if (s + 1 < LCH) {
      int r2 = row + 1;
      dt = bf2f(deltab[(size_t)r2 * DI + d]);
      xv = bf2f(xconv[(size_t)r2 * DI + d]);
      zv = bf2f(zb[(size_t)r2 * DI + d]);
      const float4* q4 = (const float4*)(BC + (size_t)r2 * 32);
#pragma unroll
      for (int i = 0; i < 8; ++i) q[i] = q4[i];
    }
    float dxv = dtc * xvc;
    float yp[4] = {0.f, 0.f, 0.f, 0.f};
#pragma unroll
    for (int n = 0; n < NST; ++n) {
      float a = fexp2(dtc * An[n]);
      h[n] = fmaf(a, h[n], dxv * Bm[n]);
      yp[n & 3] = fmaf(h[n], Cm[n], yp[n & 3]);
    }
    float y = (yp[0] + yp[1]) + (yp[2] + yp[3]);
    float sz = zvc / (1.f + __expf(-zvc));
    ys[(size_t)row * DI + d] = f2bf((y + Dd * xvc) * sz);
  }
}

// ---------------------------------------------------------------- host ----
extern "C" void kernel_launch(void* const* d_in, const int* in_sizes, int n_in,
                              void* d_out, int out_size, void* d_ws,
                              size_t ws_size, hipStream_t stream) {
  (void)in_sizes; (void)n_in; (void)out_size;
  const void* x        = d_in[0];
  const void* rms1_w   = d_in[1];
  const void* rms2_w   = d_in[2];
  const void* in_proj  = d_in[3];
  const void* conv_w   = d_in[4];
  const void* conv_b   = d_in[5];
  const void* x_proj   = d_in[6];
  const void* dt_w     = d_in[7];
  const void* dt_b     = d_in[8];
  const void* A_log    = d_in[9];
  const void* Dp       = d_in[10];
  const void* out_proj = d_in[11];
  const void* gamma    = d_in[12];
  const void* beta     = d_in[13];
  const void* gate_w   = d_in[14];
  const void* up_w     = d_in[15];
  const void* down_w   = d_in[16];

  char* ws = (char*)d_ws;
  size_t off = 0;
  auto alloc = [&](size_t bytes) -> void* {
    void* p = ws + off;
    off = (off + bytes + 255) & ~(size_t)255;
    return p;
  };
  // weights (persistent), bf16 [N][K]
  u16*   W1T   = (u16*)alloc((size_t)1536 * 384 * 2);
  u16*   WCT   = (u16*)alloc((size_t)4 * 768 * 768 * 2);
  u16*   W45T  = (u16*)alloc((size_t)896 * 768 * 2);
  u16*   W5T   = (u16*)alloc((size_t)384 * 768 * 2);
  u16*   W6T   = (u16*)alloc((size_t)2048 * 384 * 2);
  u16*   W7T   = (u16*)alloc((size_t)384 * 1024 * 2);
  float* An2T  = (float*)alloc((size_t)16 * 768 * 4);
  u16*   vecs  = (u16*)alloc(3840 * 2);
  u16*   WinX  = (u16*)alloc((size_t)384 * 768 * 2);
  u16*   WcombT= (u16*)alloc((size_t)768 * 1536 * 2);
  // activations
  u16*   h1pad = (u16*)alloc((size_t)4 * 2051 * 384 * 2);  // prep -> gemm_xz
  u16*   zbuf  = (u16*)alloc((size_t)8192 * 768 * 2);      // gemm_xz -> scan3
  u16*   xconv = (u16*)alloc((size_t)8192 * 768 * 2);      // gemm_xz -> scan3
  u16*   deltab= (u16*)alloc((size_t)8192 * 768 * 2);      // gemm2 -> scan3
  float* BCb   = (float*)alloc((size_t)8192 * 32 * 4);     // gemm2 -> scan3
  float* hl    = (float*)alloc((size_t)196608 * 16 * 4);   // scan1 -> scan2
  float* Pb    = (float*)alloc((size_t)196608 * 16 * 4);   // scan1 -> scan2
  float* hin   = (float*)alloc((size_t)196608 * 16 * 4);   // scan2 -> scan3
  // ~96 MB total.  Aliases (write begins after host region's last read):
  u16*   ys   = (u16*)hl;     // scan3 -> gemm3  (hl dead after scan2)
  float* outm = Pb;           // gemm3 -> lnrms  (Pb dead after scan2)
  float* x2f  = hin;          // lnrms -> gemm5  (hin dead after scan3)
  u16*   h2   = h1pad;        // lnrms -> gemm_gu (h1pad dead after gemm_xz)
  u16*   hid  = (u16*)hl;     // gemm_gu -> gemm5 (ys dead after gemm3,
                              //   Pb=outm dead after lnrms; spans both)

  if (off > ws_size) return;  // ws-too-small signal: absmax == max|ref|

  // prep: tiled weight transposes + rms1 + WinX + An2T + vecs + halo
  k_prep<<<6565, 256, 0, stream>>>(
      x, in_proj, conv_w, dt_w, x_proj, out_proj, gate_w, up_w, down_w,
      A_log, conv_b, dt_b, Dp, rms1_w, rms2_w, gamma, beta,
      W1T, WCT, W45T, W5T, W6T, W7T, An2T, vecs, WinX, h1pad);

  // Wcomb[tap] = Win_x @ Wc[tap] -> WcombT [768][4*384]
  gemm_bt<6, 128, 128, 768><<<dim3(3, 6, 4), 256, 0, stream>>>(
      WinX, WCT, nullptr, nullptr, WcombT, nullptr, nullptr, nullptr, nullptr);

  // merged NT=64: y<12 -> xconv (K=1536, silu) ; y>=12 -> zbuf (K=384)
  gemm_xz<<<dim3(128, 24), 256, 0, stream>>>(
      h1pad, WcombT, W1T + (size_t)768 * 384, xconv, zbuf, vecs + V_CB);

  // delta = softplus(x_conv@dt_w + b) (bf16) ; BC = x_conv@x_proj (f32)
  // NT=64: 13 y-tiles cover n 0..831 (>= 800 needed)
  gemm_bt<2, 64, 64, 768><<<dim3(128, 13), 256, 0, stream>>>(
      xconv, W45T, nullptr, BCb, deltab, nullptr, vecs + V_DB, nullptr,
      nullptr);

  k_scan1<<<768, 256, 0, stream>>>(deltab, xconv, BCb, An2T, hl, Pb);
  k_scan2<<<192, 256, 0, stream>>>(hl, Pb, hin);
  k_scan3<<<768, 256, 0, stream>>>(deltab, xconv, BCb, An2T, hin, zbuf, vecs,
                                   ys);

  // out = ys @ out_proj (f32)
  gemm_bt<3, 64, 128, 768><<<dim3(128, 3), 256, 0, stream>>>(
      ys, W5T, outm, nullptr, nullptr, nullptr, nullptr, nullptr, nullptr);
  k_lnrms<<<8192, 128, 0, stream>>>(outm, x, rms1_w, vecs, x2f, h2);

  // fused gate|up GEMM + GLU -> hid ; down + residual -> out
  gemm_gu<<<dim3(128, 8), 256, 0, stream>>>(h2, W6T, hid);
  gemm_bt<5, 64, 128, 1024><<<dim3(128, 3), 256, 0, stream>>>(
      hid, W7T, (float*)d_out, nullptr, (u16*)d_out, nullptr, nullptr, x2f,
      rms1_w);
}